// Round 1
// baseline (1140.563 us; speedup 1.0000x reference)
//
#include <hip/hip_runtime.h>
#include <hip/hip_bf16.h>
#include <math.h>

#define NHEAD 12
#define MDIM 32
#define CDIM 384
#define BATCH 4
#define NTOK 3137
#define NPIX 3136
#define NXDIM 56
#define WW 7
#define W2 49
#define NKEY 442
#define NEGV -1000000000.0f
#define QSCALE 0.17677669529663687f

typedef unsigned int u32;

__device__ __forceinline__ float bf_lo(u32 u){ return __uint_as_float(u << 16); }
__device__ __forceinline__ float bf_hi(u32 u){ return __uint_as_float(u & 0xffff0000u); }
__device__ __forceinline__ u32 pk_bf16(float a, float b){
  unsigned short x = __builtin_bit_cast(unsigned short, __float2bfloat16(a));
  unsigned short y = __builtin_bit_cast(unsigned short, __float2bfloat16(b));
  return (u32)x | ((u32)y << 16);
}

// ---------------- K1: fused qkv projection GEMM ----------------
// rows = B*NTOK (=12548), cols = 384(q) + 768(kv) + 768(kvg) = 1920, K = 384
__global__ __launch_bounds__(256) void k_qkv(
    const float* __restrict__ x, const float* __restrict__ wq,
    const float* __restrict__ wkv, const float* __restrict__ wkvg,
    float* __restrict__ qb, float* __restrict__ kb, float* __restrict__ vb,
    float* __restrict__ kgb, float* __restrict__ vgb)
{
  __shared__ float As[16][64];
  __shared__ float Bs[16][64];
  const int nrows = BATCH * NTOK;
  int row0 = blockIdx.x * 64;
  int cb = blockIdx.y, col0 = cb * 64;
  const float* Wp; int ld, coff;
  if (cb < 6)       { Wp = wq;   ld = CDIM; coff = col0; }
  else if (cb < 18) { Wp = wkv;  ld = 768;  coff = col0 - 384; }
  else              { Wp = wkvg; ld = 768;  coff = col0 - 1152; }
  int tid = threadIdx.x, tx = tid & 15, ty = tid >> 4;
  int lr = tid >> 2, lk = (tid & 3) * 4;   // A loader: row lr, k-quad lk
  int bk = tid >> 4, bc = (tid & 15) * 4;  // B loader: k bk, col-quad bc
  float acc[4][4] = {};
  for (int k0 = 0; k0 < CDIM; k0 += 16) {
    float4 av = make_float4(0.f, 0.f, 0.f, 0.f);
    int grow = row0 + lr;
    if (grow < nrows) av = *(const float4*)(x + (size_t)grow * CDIM + k0 + lk);
    float4 bv = *(const float4*)(Wp + (size_t)(k0 + bk) * ld + coff + bc);
    As[lk + 0][lr] = av.x; As[lk + 1][lr] = av.y;
    As[lk + 2][lr] = av.z; As[lk + 3][lr] = av.w;
    *(float4*)&Bs[bk][bc] = bv;
    __syncthreads();
#pragma unroll
    for (int kk = 0; kk < 16; ++kk) {
      float4 a4 = *(const float4*)&As[kk][ty * 4];
      float4 b4 = *(const float4*)&Bs[kk][tx * 4];
      float a[4] = {a4.x, a4.y, a4.z, a4.w};
      float b[4] = {b4.x, b4.y, b4.z, b4.w};
#pragma unroll
      for (int i = 0; i < 4; ++i)
#pragma unroll
        for (int j = 0; j < 4; ++j) acc[i][j] += a[i] * b[j];
    }
    __syncthreads();
  }
#pragma unroll
  for (int i = 0; i < 4; ++i) {
    int r = row0 + ty * 4 + i;
    if (r >= nrows) break;
    int b = r / NTOK, n = r % NTOK;
#pragma unroll
    for (int j = 0; j < 4; ++j) {
      int gc = col0 + tx * 4 + j;
      float val = acc[i][j];
      if (gc < 384) {
        if (n > 0) {
          int h = gc >> 5, d = gc & 31;
          qb[(((size_t)b * NHEAD + h) * NPIX + (n - 1)) * MDIM + d] = val * QSCALE;
        }
      } else if (gc < 1152) {
        int c2 = gc - 384;
        int cm = (c2 < 384) ? c2 : c2 - 384;
        int h = cm >> 5, d = cm & 31;
        float* dst = (c2 < 384) ? kb : vb;
        dst[(((size_t)b * NHEAD + h) * NTOK + n) * MDIM + d] = val;
      } else {
        int c3 = gc - 1152;
        int cm = (c3 < 384) ? c3 : c3 - 384;
        int h = cm >> 5, d = cm & 31;
        float* dst = (c3 < 384) ? kgb : vgb;
        dst[(((size_t)b * NHEAD + h) * NTOK + n) * MDIM + d] = val;
      }
    }
  }
}

// ---------------- K2: windowed local attention ----------------
// grid: (64 windows, B*H). 256 thr = 4 waves; wave = key-chunk, lane = query.
__global__ __launch_bounds__(256) void k_local(
    const float* __restrict__ qb, const float* __restrict__ kb, const float* __restrict__ vb,
    const float* __restrict__ lbt, const float* __restrict__ g2l, const int* __restrict__ rel,
    float* __restrict__ x1pre)
{
  __shared__ u32 smem[NKEY * 16 * 2];  // Ks,Vs as packed bf16 pairs (56576 B)
  u32* KsU = smem;
  u32* VsU = smem + NKEY * 16;
  int tid = threadIdx.x, lane = tid & 63, wv = tid >> 6;
  int bh = blockIdx.y, b = bh / NHEAD, h = bh % NHEAD;
  int wid = blockIdx.x, mi = wid >> 3, nj = wid & 7;
  const float* kbh = kb + (size_t)bh * NTOK * MDIM;
  const float* vbh = vb + (size_t)bh * NTOK * MDIM;
  // stage K/V (zeros for invalid neighbor windows)
  for (int i = tid; i < NKEY * 8; i += 256) {
    int key = i >> 3, seg = i & 7;
    int n = 0; bool val = true;
    if (key > 0) {
      int j = key - 1, kk = j / 49, t = j - kk * 49;
      int a = kk / 3 - 1, bb = kk % 3 - 1;
      int px = mi + a, py = nj + bb;
      val = (px >= 0) && (px < 8) && (py >= 0) && (py < 8);
      n = val ? (1 + (px * WW + t / WW) * NXDIM + (py * WW + t % WW)) : 0;
    }
    float4 kv4 = make_float4(0.f,0.f,0.f,0.f), vv4 = make_float4(0.f,0.f,0.f,0.f);
    if (val) {
      kv4 = *(const float4*)(kbh + (size_t)n * MDIM + seg * 4);
      vv4 = *(const float4*)(vbh + (size_t)n * MDIM + seg * 4);
    }
    KsU[key * 16 + seg * 2]     = pk_bf16(kv4.x, kv4.y);
    KsU[key * 16 + seg * 2 + 1] = pk_bf16(kv4.z, kv4.w);
    VsU[key * 16 + seg * 2]     = pk_bf16(vv4.x, vv4.y);
    VsU[key * 16 + seg * 2 + 1] = pk_bf16(vv4.z, vv4.w);
  }
  int l = lane, ll = (l < W2) ? l : 0;
  int qpix = (mi * WW + ll / WW) * NXDIM + (nj * WW + ll % WW);
  float ql[32];
  {
    const float4* qp = (const float4*)(qb + ((size_t)bh * NPIX + qpix) * MDIM);
#pragma unroll
    for (int g = 0; g < 8; ++g) {
      float4 t4 = qp[g];
      ql[4*g] = t4.x; ql[4*g+1] = t4.y; ql[4*g+2] = t4.z; ql[4*g+3] = t4.w;
    }
  }
  bool validw[9];
#pragma unroll
  for (int kk = 0; kk < 9; ++kk) {
    int px = mi + kk / 3 - 1, py = nj + kk % 3 - 1;
    validw[kk] = (px >= 0) && (px < 8) && (py >= 0) && (py < 8);
  }
  float g2l1 = g2l[NHEAD + h];
  __syncthreads();

  auto dot32 = [&](const u32* kr) -> float {
    const uint4* k4 = (const uint4*)kr;
    float dp0 = 0.f, dp1 = 0.f, dp2 = 0.f, dp3 = 0.f;
#pragma unroll
    for (int g = 0; g < 4; ++g) {
      uint4 u = k4[g];
      dp0 += ql[8*g+0]*bf_lo(u.x) + ql[8*g+1]*bf_hi(u.x);
      dp1 += ql[8*g+2]*bf_lo(u.y) + ql[8*g+3]*bf_hi(u.y);
      dp2 += ql[8*g+4]*bf_lo(u.z) + ql[8*g+5]*bf_hi(u.z);
      dp3 += ql[8*g+6]*bf_lo(u.w) + ql[8*g+7]*bf_hi(u.w);
    }
    return (dp0 + dp1) + (dp2 + dp3);
  };

  int k0 = wv * 111, k1 = min(NKEY, k0 + 111);
  float m = -INFINITY, s = 0.f, acc[32] = {};
  for (int j = k0; j < k1; ++j) {
    float logit;
    if (j == 0) {
      logit = dot32(KsU) + g2l1;
    } else {
      int kk = (j - 1) / 49;
      if (validw[kk])
        logit = dot32(KsU + j * 16) + lbt[rel[ll * 441 + (j - 1)] * NHEAD + h];
      else
        logit = NEGV;
    }
    if (logit > m) {
      float corr = __expf(m - logit);
      s *= corr;
#pragma unroll
      for (int d = 0; d < 32; ++d) acc[d] *= corr;
      m = logit;
    }
    float p = __expf(logit - m);
    s += p;
    const uint4* vr = (const uint4*)(VsU + j * 16);
#pragma unroll
    for (int g = 0; g < 4; ++g) {
      uint4 u = vr[g];
      acc[8*g+0] += p * bf_lo(u.x); acc[8*g+1] += p * bf_hi(u.x);
      acc[8*g+2] += p * bf_lo(u.y); acc[8*g+3] += p * bf_hi(u.y);
      acc[8*g+4] += p * bf_lo(u.z); acc[8*g+5] += p * bf_hi(u.z);
      acc[8*g+6] += p * bf_lo(u.w); acc[8*g+7] += p * bf_hi(u.w);
    }
  }
  __syncthreads();  // done with Ks/Vs; alias combine buffer
  float* cmb = (float*)smem;  // [4][49][34]
  if (l < W2) {
    float* cp = cmb + (wv * W2 + l) * 34;
    cp[0] = m; cp[1] = s;
#pragma unroll
    for (int d = 0; d < 32; ++d) cp[2 + d] = acc[d];
  }
  __syncthreads();
  if (wv == 0 && l < W2) {
    float M = -INFINITY;
#pragma unroll
    for (int w = 0; w < 4; ++w) M = fmaxf(M, cmb[(w * W2 + l) * 34]);
    float S = 0.f, o[32] = {};
#pragma unroll
    for (int w = 0; w < 4; ++w) {
      float* cp = cmb + (w * W2 + l) * 34;
      float f = __expf(cp[0] - M);
      S += cp[1] * f;
#pragma unroll
      for (int d = 0; d < 32; ++d) o[d] += cp[2 + d] * f;
    }
    float inv = 1.f / S;
    float* op = x1pre + ((size_t)b * NPIX + qpix) * CDIM + h * MDIM;
#pragma unroll
    for (int g = 0; g < 8; ++g)
      *(float4*)(op + 4 * g) = make_float4(o[4*g]*inv, o[4*g+1]*inv, o[4*g+2]*inv, o[4*g+3]*inv);
  }
}

// ---------------- K3: global token attention ----------------
__global__ __launch_bounds__(256) void k_glob(
    const float* __restrict__ x, const float* __restrict__ wqg,
    const float* __restrict__ kgb, const float* __restrict__ vgb,
    const float* __restrict__ g2l, const float* __restrict__ g2g,
    float* __restrict__ x0pre)
{
  int bh = blockIdx.x, b = bh / NHEAD, h = bh % NHEAD;
  __shared__ float qg[32];
  __shared__ float lg[NTOK];
  __shared__ float red[4];
  __shared__ float accw[4][32];
  __shared__ float sw[4];
  int tid = threadIdx.x, wv = tid >> 6;
  const float* xr = x + (size_t)b * NTOK * CDIM;
  if (tid < 32) {
    float a = 0.f;
    for (int kk = 0; kk < CDIM; ++kk) a += xr[kk] * wqg[(size_t)kk * CDIM + h * MDIM + tid];
    qg[tid] = a * QSCALE;
  }
  __syncthreads();
  const float* kbh = kgb + (size_t)bh * NTOK * MDIM;
  const float* vbh = vgb + (size_t)bh * NTOK * MDIM;
  float b0 = g2g[h], b1 = g2l[h];
  float lmax = -INFINITY;
  for (int n = tid; n < NTOK; n += 256) {
    const float4* kr = (const float4*)(kbh + (size_t)n * MDIM);
    float dot = 0.f;
#pragma unroll
    for (int g = 0; g < 8; ++g) {
      float4 t4 = kr[g];
      dot += qg[4*g]*t4.x + qg[4*g+1]*t4.y + qg[4*g+2]*t4.z + qg[4*g+3]*t4.w;
    }
    dot += (n == 0) ? b0 : b1;
    lg[n] = dot;
    lmax = fmaxf(lmax, dot);
  }
#pragma unroll
  for (int off = 32; off; off >>= 1) lmax = fmaxf(lmax, __shfl_down(lmax, off));
  if ((tid & 63) == 0) red[wv] = lmax;
  __syncthreads();
  float M = fmaxf(fmaxf(red[0], red[1]), fmaxf(red[2], red[3]));
  float s = 0.f, acc[32] = {};
  for (int n = tid; n < NTOK; n += 256) {
    float p = __expf(lg[n] - M);
    s += p;
    const float4* vr = (const float4*)(vbh + (size_t)n * MDIM);
#pragma unroll
    for (int g = 0; g < 8; ++g) {
      float4 t4 = vr[g];
      acc[4*g]   += p * t4.x; acc[4*g+1] += p * t4.y;
      acc[4*g+2] += p * t4.z; acc[4*g+3] += p * t4.w;
    }
  }
#pragma unroll
  for (int off = 32; off; off >>= 1) {
    s += __shfl_down(s, off);
#pragma unroll
    for (int d = 0; d < 32; ++d) acc[d] += __shfl_down(acc[d], off);
  }
  if ((tid & 63) == 0) {
    sw[wv] = s;
#pragma unroll
    for (int d = 0; d < 32; ++d) accw[wv][d] = acc[d];
  }
  __syncthreads();
  if (tid < 32) {
    float S = sw[0] + sw[1] + sw[2] + sw[3];
    float o = accw[0][tid] + accw[1][tid] + accw[2][tid] + accw[3][tid];
    x0pre[(size_t)b * CDIM + h * MDIM + tid] = o / S;
  }
}

// ---------------- K4: x1 output projection ----------------
__global__ __launch_bounds__(256) void k_proj(
    const float* __restrict__ a, const float* __restrict__ wproj,
    const float* __restrict__ bproj, float* __restrict__ out)
{
  __shared__ float As[16][64];
  __shared__ float Bs[16][64];
  int row0 = blockIdx.x * 64, col0 = blockIdx.y * 64;
  int tid = threadIdx.x, tx = tid & 15, ty = tid >> 4;
  int lr = tid >> 2, lk = (tid & 3) * 4;
  int bk = tid >> 4, bc = (tid & 15) * 4;
  float acc[4][4] = {};
  for (int k0 = 0; k0 < CDIM; k0 += 16) {
    float4 av = *(const float4*)(a + (size_t)(row0 + lr) * CDIM + k0 + lk);
    float4 bv = *(const float4*)(wproj + (size_t)(k0 + bk) * CDIM + col0 + bc);
    As[lk + 0][lr] = av.x; As[lk + 1][lr] = av.y;
    As[lk + 2][lr] = av.z; As[lk + 3][lr] = av.w;
    *(float4*)&Bs[bk][bc] = bv;
    __syncthreads();
#pragma unroll
    for (int kk = 0; kk < 16; ++kk) {
      float4 a4 = *(const float4*)&As[kk][ty * 4];
      float4 b4 = *(const float4*)&Bs[kk][tx * 4];
      float av2[4] = {a4.x, a4.y, a4.z, a4.w};
      float bv2[4] = {b4.x, b4.y, b4.z, b4.w};
#pragma unroll
      for (int i = 0; i < 4; ++i)
#pragma unroll
        for (int j = 0; j < 4; ++j) acc[i][j] += av2[i] * bv2[j];
    }
    __syncthreads();
  }
#pragma unroll
  for (int i = 0; i < 4; ++i) {
    int r = row0 + ty * 4 + i;
    int b = r / NPIX, p = r % NPIX;
#pragma unroll
    for (int j = 0; j < 4; ++j) {
      int c = col0 + tx * 4 + j;
      out[((size_t)b * NTOK + 1 + p) * CDIM + c] = acc[i][j] + bproj[c];
    }
  }
}

// ---------------- K5: x0 output projection (tiny) ----------------
__global__ void k_x0proj(const float* __restrict__ x0pre, const float* __restrict__ wprojg,
                         const float* __restrict__ bprojg, float* __restrict__ out)
{
  int b = blockIdx.x, c = threadIdx.x;
  __shared__ float xr[CDIM];
  xr[c] = x0pre[(size_t)b * CDIM + c];
  __syncthreads();
  float acc = bprojg[c];
  for (int kk = 0; kk < CDIM; ++kk) acc += xr[kk] * wprojg[(size_t)kk * CDIM + c];
  out[(size_t)b * NTOK * CDIM + c] = acc;
}

extern "C" void kernel_launch(void* const* d_in, const int* in_sizes, int n_in,
                              void* d_out, int out_size, void* d_ws, size_t ws_size,
                              hipStream_t stream)
{
  const float* x      = (const float*)d_in[0];
  const float* wq     = (const float*)d_in[1];
  const float* wkv    = (const float*)d_in[2];
  const float* wproj  = (const float*)d_in[3];
  const float* bproj  = (const float*)d_in[4];
  const float* wqg    = (const float*)d_in[5];
  const float* wkvg   = (const float*)d_in[6];
  const float* wprojg = (const float*)d_in[7];
  const float* bprojg = (const float*)d_in[8];
  const float* lbt    = (const float*)d_in[9];
  const float* g2l    = (const float*)d_in[10];
  const float* g2g    = (const float*)d_in[11];
  const int*   rel    = (const int*)d_in[12];
  float* out = (float*)d_out;
  float* ws = (float*)d_ws;

  size_t off = 0;
  float* qb    = ws + off; off += (size_t)BATCH * NHEAD * NPIX * MDIM;
  float* kb    = ws + off; off += (size_t)BATCH * NHEAD * NTOK * MDIM;
  float* vb    = ws + off; off += (size_t)BATCH * NHEAD * NTOK * MDIM;
  float* kgb   = ws + off; off += (size_t)BATCH * NHEAD * NTOK * MDIM;
  float* vgb   = ws + off; off += (size_t)BATCH * NHEAD * NTOK * MDIM;
  float* x1pre = ws + off; off += (size_t)BATCH * NPIX * CDIM;
  float* x0pre = ws + off; off += (size_t)BATCH * CDIM;

  dim3 g1((BATCH * NTOK + 63) / 64, 30);
  k_qkv<<<g1, 256, 0, stream>>>(x, wq, wkv, wkvg, qb, kb, vb, kgb, vgb);

  dim3 g2(64, BATCH * NHEAD);
  k_local<<<g2, 256, 0, stream>>>(qb, kb, vb, lbt, g2l, rel, x1pre);

  k_glob<<<BATCH * NHEAD, 256, 0, stream>>>(x, wqg, kgb, vgb, g2l, g2g, x0pre);

  dim3 g4(BATCH * NPIX / 64, 6);
  k_proj<<<g4, 256, 0, stream>>>(x1pre, wproj, bproj, out);

  k_x0proj<<<BATCH, CDIM, 0, stream>>>(x0pre, wprojg, bprojg, out);
}

// Round 2
// 581.009 us; speedup vs baseline: 1.9631x; 1.9631x over previous
//
#include <hip/hip_runtime.h>
#include <hip/hip_bf16.h>
#include <math.h>

#define NHEAD 12
#define MDIM 32
#define CDIM 384
#define BATCH 4
#define NTOK 3137
#define NPIX 3136
#define NXDIM 56
#define WW 7
#define W2 49
#define NKEYP 448
#define NT 28
#define NEGV -1000000000.0f
#define QSCALE 0.17677669529663687f

typedef unsigned int u32;
typedef unsigned short u16;
typedef __attribute__((ext_vector_type(8))) short bf16x8;
typedef __attribute__((ext_vector_type(4))) float f32x4;

__device__ __forceinline__ u32 pk_bf16(float a, float b){
  u16 x = __builtin_bit_cast(u16, __float2bfloat16(a));
  u16 y = __builtin_bit_cast(u16, __float2bfloat16(b));
  return (u32)x | ((u32)y << 16);
}
__device__ __forceinline__ u16 to_bf(float a){
  return __builtin_bit_cast(u16, __float2bfloat16(a));
}

// ---------------- K1: fused qkv projection GEMM (writes q/k/v as bf16) ----------------
__global__ __launch_bounds__(256) void k_qkv(
    const float* __restrict__ x, const float* __restrict__ wq,
    const float* __restrict__ wkv, const float* __restrict__ wkvg,
    u16* __restrict__ qb, u16* __restrict__ kb, u16* __restrict__ vb,
    float* __restrict__ kgb, float* __restrict__ vgb)
{
  __shared__ float As[16][64];
  __shared__ float Bs[16][64];
  const int nrows = BATCH * NTOK;
  int row0 = blockIdx.x * 64;
  int cb = blockIdx.y, col0 = cb * 64;
  const float* Wp; int ld, coff;
  if (cb < 6)       { Wp = wq;   ld = CDIM; coff = col0; }
  else if (cb < 18) { Wp = wkv;  ld = 768;  coff = col0 - 384; }
  else              { Wp = wkvg; ld = 768;  coff = col0 - 1152; }
  int tid = threadIdx.x, tx = tid & 15, ty = tid >> 4;
  int lr = tid >> 2, lk = (tid & 3) * 4;
  int bk = tid >> 4, bc = (tid & 15) * 4;
  float acc[4][4] = {};
  for (int k0 = 0; k0 < CDIM; k0 += 16) {
    float4 av = make_float4(0.f, 0.f, 0.f, 0.f);
    int grow = row0 + lr;
    if (grow < nrows) av = *(const float4*)(x + (size_t)grow * CDIM + k0 + lk);
    float4 bv = *(const float4*)(Wp + (size_t)(k0 + bk) * ld + coff + bc);
    As[lk + 0][lr] = av.x; As[lk + 1][lr] = av.y;
    As[lk + 2][lr] = av.z; As[lk + 3][lr] = av.w;
    *(float4*)&Bs[bk][bc] = bv;
    __syncthreads();
#pragma unroll
    for (int kk = 0; kk < 16; ++kk) {
      float4 a4 = *(const float4*)&As[kk][ty * 4];
      float4 b4 = *(const float4*)&Bs[kk][tx * 4];
      float a[4] = {a4.x, a4.y, a4.z, a4.w};
      float b[4] = {b4.x, b4.y, b4.z, b4.w};
#pragma unroll
      for (int i = 0; i < 4; ++i)
#pragma unroll
        for (int j = 0; j < 4; ++j) acc[i][j] += a[i] * b[j];
    }
    __syncthreads();
  }
#pragma unroll
  for (int i = 0; i < 4; ++i) {
    int r = row0 + ty * 4 + i;
    if (r >= nrows) break;
    int b = r / NTOK, n = r % NTOK;
#pragma unroll
    for (int j = 0; j < 4; ++j) {
      int gc = col0 + tx * 4 + j;
      float val = acc[i][j];
      if (gc < 384) {
        if (n > 0) {
          int h = gc >> 5, d = gc & 31;
          qb[(((size_t)b * NHEAD + h) * NPIX + (n - 1)) * MDIM + d] = to_bf(val * QSCALE);
        }
      } else if (gc < 1152) {
        int c2 = gc - 384;
        int cm = (c2 < 384) ? c2 : c2 - 384;
        int h = cm >> 5, d = cm & 31;
        u16* dst = (c2 < 384) ? kb : vb;
        dst[(((size_t)b * NHEAD + h) * NTOK + n) * MDIM + d] = to_bf(val);
      } else {
        int c3 = gc - 1152;
        int cm = (c3 < 384) ? c3 : c3 - 384;
        int h = cm >> 5, d = cm & 31;
        float* dst = (c3 < 384) ? kgb : vgb;
        dst[(((size_t)b * NHEAD + h) * NTOK + n) * MDIM + d] = val;
      }
    }
  }
}

// ---------------- K1b: precompute bias in MFMA C-fragment layout ----------------
// bias_pk[h][w][t][lane] = float4 over r; value for (query=16w+(lane&15), key=16t+4*(lane>>4)+r)
__global__ __launch_bounds__(256) void k_bias(
    const float* __restrict__ lbt, const float* __restrict__ g2l,
    const int* __restrict__ rel, float* __restrict__ bias_pk)
{
  int idx = blockIdx.x * 256 + threadIdx.x;
  if (idx >= NHEAD * 4 * NT * 64) return;
  int lane = idx & 63;
  int t = (idx >> 6) % NT;
  int hw = (idx >> 6) / NT;
  int w = hw & 3, h = hw >> 2;
  int g = lane >> 4;
  int q = 16 * w + (lane & 15); if (q > 48) q = 48;
  float4 v;
  float* vp = (float*)&v;
#pragma unroll
  for (int r = 0; r < 4; ++r) {
    int k = 16 * t + 4 * g + r;
    float val;
    if (k == 0) val = g2l[NHEAD + h];
    else if (k <= 441) val = lbt[rel[q * 441 + (k - 1)] * NHEAD + h];
    else val = NEGV;
    vp[r] = val;
  }
  *(float4*)(bias_pk + (size_t)idx * 4) = v;
}

// ---------------- K2: windowed local attention via MFMA ----------------
// grid: (64 windows, B*H), 256 threads = 4 waves; wave w owns queries 16w..16w+15.
__device__ __forceinline__ int key_tok(int key, int mi, int nj, bool& valid){
  if (key == 0) { valid = true; return 0; }
  if (key > 441) { valid = false; return 0; }
  int j = key - 1, kk = j / 49, t = j - kk * 49;
  int px = mi + kk / 3 - 1, py = nj + kk % 3 - 1;
  valid = (px >= 0) && (px < 8) && (py >= 0) && (py < 8);
  return valid ? (1 + (px * WW + t / WW) * NXDIM + (py * WW + t % WW)) : 0;
}

__global__ __launch_bounds__(256) void k_local(
    const u16* __restrict__ qb, const u16* __restrict__ kb, const u16* __restrict__ vb,
    const float* __restrict__ bias_pk, float* __restrict__ x1pre)
{
  __shared__ __align__(16) u16 Ks[NKEYP * 40];   // [448 keys][32 dims +8 pad]
  __shared__ __align__(16) u16 Vt[32 * 456];     // [32 dims][448 keys +8 pad] (transposed)
  __shared__ __align__(16) u16 Pbuf[4 * 640];    // per-wave P chunk [16 q][40 keys]
  __shared__ __align__(16) float Msk[NKEYP];     // 0 or NEG per key

  int tid = threadIdx.x, lane = tid & 63, wv = tid >> 6;
  int r16 = lane & 15, g = lane >> 4;
  int bh = blockIdx.y, b = bh / NHEAD, h = bh % NHEAD;
  int wid = blockIdx.x, mi = wid >> 3, nj = wid & 7;
  const u16* kbh = kb + (size_t)bh * NTOK * MDIM;
  const u16* vbh = vb + (size_t)bh * NTOK * MDIM;
  const u16* qbh = qb + (size_t)bh * NPIX * MDIM;

  // stage K rows (bf16, zero for invalid)
  for (int i = tid; i < NKEYP * 4; i += 256) {
    int key = i >> 2, seg = i & 3;
    bool val; int n = key_tok(key, mi, nj, val);
    uint4 kv = make_uint4(0, 0, 0, 0);
    if (val) kv = *(const uint4*)(kbh + (size_t)n * MDIM + seg * 8);
    *(uint4*)&Ks[key * 40 + seg * 8] = kv;
  }
  // stage V transposed: Vt[d][key]
  for (int i = tid; i < 224 * 8; i += 256) {
    int kp = i >> 3, seg = i & 7;
    bool v0, v1;
    int n0 = key_tok(2 * kp, mi, nj, v0);
    int n1 = key_tok(2 * kp + 1, mi, nj, v1);
    uint2 a0 = make_uint2(0, 0), a1 = make_uint2(0, 0);
    if (v0) a0 = *(const uint2*)(vbh + (size_t)n0 * MDIM + seg * 4);
    if (v1) a1 = *(const uint2*)(vbh + (size_t)n1 * MDIM + seg * 4);
    int d0 = seg * 4;
    *(u32*)&Vt[(d0 + 0) * 456 + 2 * kp] = (a0.x & 0xffffu) | ((a1.x & 0xffffu) << 16);
    *(u32*)&Vt[(d0 + 1) * 456 + 2 * kp] = (a0.x >> 16)     | (a1.x & 0xffff0000u);
    *(u32*)&Vt[(d0 + 2) * 456 + 2 * kp] = (a0.y & 0xffffu) | ((a1.y & 0xffffu) << 16);
    *(u32*)&Vt[(d0 + 3) * 456 + 2 * kp] = (a0.y >> 16)     | (a1.y & 0xffff0000u);
  }
  // mask per key
  for (int i = tid; i < NKEYP; i += 256) {
    float mv = NEGV;
    if (i == 0) mv = 0.f;
    else if (i <= 441) {
      int j = i - 1, kk = j / 49;
      int px = mi + kk / 3 - 1, py = nj + kk % 3 - 1;
      mv = ((px >= 0) && (px < 8) && (py >= 0) && (py < 8)) ? 0.f : NEGV;
    }
    Msk[i] = mv;
  }
  // Q fragment (B-operand): lane holds Q[q=16wv+r16][8g..8g+7]
  int q0 = wv * 16 + r16, qc = (q0 < 49) ? q0 : 48;
  int qpix = (mi * WW + qc / WW) * NXDIM + (nj * WW + qc % WW);
  uint4 qv = *(const uint4*)(qbh + (size_t)qpix * MDIM + 8 * g);
  bf16x8 qf = __builtin_bit_cast(bf16x8, qv);
  __syncthreads();

  // QK^T (swapped): acc[t] holds S^T[key=16t+4g+r][query=16wv+r16], bias pre-added via C-in
  f32x4 acc[NT];
  const float4* bp = (const float4*)bias_pk + ((size_t)(h * 4 + wv) * NT) * 64 + lane;
#pragma unroll
  for (int t = 0; t < NT; ++t) {
    float4 bv = bp[t * 64];
    float4 mv = *(const float4*)&Msk[t * 16 + 4 * g];
    f32x4 cin = {bv.x + mv.x, bv.y + mv.y, bv.z + mv.z, bv.w + mv.w};
    uint4 av = *(const uint4*)&Ks[(t * 16 + r16) * 40 + 8 * g];
    acc[t] = __builtin_amdgcn_mfma_f32_16x16x32_bf16(
        __builtin_bit_cast(bf16x8, av), qf, cin, 0, 0, 0);
  }
  // softmax: per-lane over 112 regs, then across the 4 g-groups
  float mx = -INFINITY;
#pragma unroll
  for (int t = 0; t < NT; ++t)
    mx = fmaxf(mx, fmaxf(fmaxf(acc[t].x, acc[t].y), fmaxf(acc[t].z, acc[t].w)));
  mx = fmaxf(mx, __shfl_xor(mx, 16));
  mx = fmaxf(mx, __shfl_xor(mx, 32));
  float ssum = 0.f;
#pragma unroll
  for (int t = 0; t < NT; ++t) {
    acc[t].x = __expf(acc[t].x - mx); ssum += acc[t].x;
    acc[t].y = __expf(acc[t].y - mx); ssum += acc[t].y;
    acc[t].z = __expf(acc[t].z - mx); ssum += acc[t].z;
    acc[t].w = __expf(acc[t].w - mx); ssum += acc[t].w;
  }
  ssum += __shfl_xor(ssum, 16);
  ssum += __shfl_xor(ssum, 32);

  // PV: O^T = V^T @ P^T, P bounced through wave-private LDS chunk
  f32x4 o0 = {0.f, 0.f, 0.f, 0.f}, o1 = {0.f, 0.f, 0.f, 0.f};
  u16* Pb = Pbuf + wv * 640;
#pragma unroll
  for (int c = 0; c < 14; ++c) {
    f32x4 p0 = acc[2 * c], p1 = acc[2 * c + 1];
    *(u32*)&Pb[r16 * 40 + 4 * g]          = pk_bf16(p0.x, p0.y);
    *(u32*)&Pb[r16 * 40 + 4 * g + 2]      = pk_bf16(p0.z, p0.w);
    *(u32*)&Pb[r16 * 40 + 16 + 4 * g]     = pk_bf16(p1.x, p1.y);
    *(u32*)&Pb[r16 * 40 + 16 + 4 * g + 2] = pk_bf16(p1.z, p1.w);
    uint4 pv = *(uint4*)&Pb[r16 * 40 + 8 * g];
    uint4 v0 = *(const uint4*)&Vt[r16 * 456 + 32 * c + 8 * g];
    uint4 v1 = *(const uint4*)&Vt[(16 + r16) * 456 + 32 * c + 8 * g];
    o0 = __builtin_amdgcn_mfma_f32_16x16x32_bf16(
        __builtin_bit_cast(bf16x8, v0), __builtin_bit_cast(bf16x8, pv), o0, 0, 0, 0);
    o1 = __builtin_amdgcn_mfma_f32_16x16x32_bf16(
        __builtin_bit_cast(bf16x8, v1), __builtin_bit_cast(bf16x8, pv), o1, 0, 0, 0);
  }
  // store: lane holds O[q0][d], d = 4g+r (o0) and 16+4g+r (o1)
  if (q0 < 49) {
    float inv = 1.f / ssum;
    float* op = x1pre + ((size_t)b * NPIX + qpix) * CDIM + h * MDIM;
    op[4 * g + 0] = o0.x * inv; op[4 * g + 1] = o0.y * inv;
    op[4 * g + 2] = o0.z * inv; op[4 * g + 3] = o0.w * inv;
    op[16 + 4 * g + 0] = o1.x * inv; op[16 + 4 * g + 1] = o1.y * inv;
    op[16 + 4 * g + 2] = o1.z * inv; op[16 + 4 * g + 3] = o1.w * inv;
  }
}

// ---------------- K3: global token attention ----------------
__global__ __launch_bounds__(256) void k_glob(
    const float* __restrict__ x, const float* __restrict__ wqg,
    const float* __restrict__ kgb, const float* __restrict__ vgb,
    const float* __restrict__ g2l, const float* __restrict__ g2g,
    float* __restrict__ x0pre)
{
  int bh = blockIdx.x, b = bh / NHEAD, h = bh % NHEAD;
  __shared__ float qg[32];
  __shared__ float lg[NTOK];
  __shared__ float red[4];
  __shared__ float accw[4][32];
  __shared__ float sw[4];
  int tid = threadIdx.x, wv = tid >> 6;
  const float* xr = x + (size_t)b * NTOK * CDIM;
  if (tid < 32) {
    float a = 0.f;
    for (int kk = 0; kk < CDIM; ++kk) a += xr[kk] * wqg[(size_t)kk * CDIM + h * MDIM + tid];
    qg[tid] = a * QSCALE;
  }
  __syncthreads();
  const float* kbh = kgb + (size_t)bh * NTOK * MDIM;
  const float* vbh = vgb + (size_t)bh * NTOK * MDIM;
  float b0 = g2g[h], b1 = g2l[h];
  float lmax = -INFINITY;
  for (int n = tid; n < NTOK; n += 256) {
    const float4* kr = (const float4*)(kbh + (size_t)n * MDIM);
    float dot = 0.f;
#pragma unroll
    for (int gg = 0; gg < 8; ++gg) {
      float4 t4 = kr[gg];
      dot += qg[4*gg]*t4.x + qg[4*gg+1]*t4.y + qg[4*gg+2]*t4.z + qg[4*gg+3]*t4.w;
    }
    dot += (n == 0) ? b0 : b1;
    lg[n] = dot;
    lmax = fmaxf(lmax, dot);
  }
#pragma unroll
  for (int off = 32; off; off >>= 1) lmax = fmaxf(lmax, __shfl_down(lmax, off));
  if ((tid & 63) == 0) red[wv] = lmax;
  __syncthreads();
  float M = fmaxf(fmaxf(red[0], red[1]), fmaxf(red[2], red[3]));
  float s = 0.f, acc[32] = {};
  for (int n = tid; n < NTOK; n += 256) {
    float p = __expf(lg[n] - M);
    s += p;
    const float4* vr = (const float4*)(vbh + (size_t)n * MDIM);
#pragma unroll
    for (int gg = 0; gg < 8; ++gg) {
      float4 t4 = vr[gg];
      acc[4*gg]   += p * t4.x; acc[4*gg+1] += p * t4.y;
      acc[4*gg+2] += p * t4.z; acc[4*gg+3] += p * t4.w;
    }
  }
#pragma unroll
  for (int off = 32; off; off >>= 1) {
    s += __shfl_down(s, off);
#pragma unroll
    for (int d = 0; d < 32; ++d) acc[d] += __shfl_down(acc[d], off);
  }
  if ((tid & 63) == 0) {
    sw[wv] = s;
#pragma unroll
    for (int d = 0; d < 32; ++d) accw[wv][d] = acc[d];
  }
  __syncthreads();
  if (tid < 32) {
    float S = sw[0] + sw[1] + sw[2] + sw[3];
    float o = accw[0][tid] + accw[1][tid] + accw[2][tid] + accw[3][tid];
    x0pre[(size_t)b * CDIM + h * MDIM + tid] = o / S;
  }
}

// ---------------- K4: x1 output projection ----------------
__global__ __launch_bounds__(256) void k_proj(
    const float* __restrict__ a, const float* __restrict__ wproj,
    const float* __restrict__ bproj, float* __restrict__ out)
{
  __shared__ float As[16][64];
  __shared__ float Bs[16][64];
  int row0 = blockIdx.x * 64, col0 = blockIdx.y * 64;
  int tid = threadIdx.x, tx = tid & 15, ty = tid >> 4;
  int lr = tid >> 2, lk = (tid & 3) * 4;
  int bk = tid >> 4, bc = (tid & 15) * 4;
  float acc[4][4] = {};
  for (int k0 = 0; k0 < CDIM; k0 += 16) {
    float4 av = *(const float4*)(a + (size_t)(row0 + lr) * CDIM + k0 + lk);
    float4 bv = *(const float4*)(wproj + (size_t)(k0 + bk) * CDIM + col0 + bc);
    As[lk + 0][lr] = av.x; As[lk + 1][lr] = av.y;
    As[lk + 2][lr] = av.z; As[lk + 3][lr] = av.w;
    *(float4*)&Bs[bk][bc] = bv;
    __syncthreads();
#pragma unroll
    for (int kk = 0; kk < 16; ++kk) {
      float4 a4 = *(const float4*)&As[kk][ty * 4];
      float4 b4 = *(const float4*)&Bs[kk][tx * 4];
      float av2[4] = {a4.x, a4.y, a4.z, a4.w};
      float bv2[4] = {b4.x, b4.y, b4.z, b4.w};
#pragma unroll
      for (int i = 0; i < 4; ++i)
#pragma unroll
        for (int j = 0; j < 4; ++j) acc[i][j] += av2[i] * bv2[j];
    }
    __syncthreads();
  }
#pragma unroll
  for (int i = 0; i < 4; ++i) {
    int r = row0 + ty * 4 + i;
    int b = r / NPIX, p = r % NPIX;
#pragma unroll
    for (int j = 0; j < 4; ++j) {
      int c = col0 + tx * 4 + j;
      out[((size_t)b * NTOK + 1 + p) * CDIM + c] = acc[i][j] + bproj[c];
    }
  }
}

// ---------------- K5: x0 output projection (tiny) ----------------
__global__ void k_x0proj(const float* __restrict__ x0pre, const float* __restrict__ wprojg,
                         const float* __restrict__ bprojg, float* __restrict__ out)
{
  int b = blockIdx.x, c = threadIdx.x;
  __shared__ float xr[CDIM];
  xr[c] = x0pre[(size_t)b * CDIM + c];
  __syncthreads();
  float acc = bprojg[c];
  for (int kk = 0; kk < CDIM; ++kk) acc += xr[kk] * wprojg[(size_t)kk * CDIM + c];
  out[(size_t)b * NTOK * CDIM + c] = acc;
}

extern "C" void kernel_launch(void* const* d_in, const int* in_sizes, int n_in,
                              void* d_out, int out_size, void* d_ws, size_t ws_size,
                              hipStream_t stream)
{
  const float* x      = (const float*)d_in[0];
  const float* wq     = (const float*)d_in[1];
  const float* wkv    = (const float*)d_in[2];
  const float* wproj  = (const float*)d_in[3];
  const float* bproj  = (const float*)d_in[4];
  const float* wqg    = (const float*)d_in[5];
  const float* wkvg   = (const float*)d_in[6];
  const float* wprojg = (const float*)d_in[7];
  const float* bprojg = (const float*)d_in[8];
  const float* lbt    = (const float*)d_in[9];
  const float* g2l    = (const float*)d_in[10];
  const float* g2g    = (const float*)d_in[11];
  const int*   rel    = (const int*)d_in[12];
  float* out = (float*)d_out;

  char* wsb = (char*)d_ws;
  u16* qb = (u16*)wsb;      wsb += (size_t)BATCH * NHEAD * NPIX * MDIM * 2;
  u16* kb = (u16*)wsb;      wsb += (size_t)BATCH * NHEAD * NTOK * MDIM * 2;
  u16* vb = (u16*)wsb;      wsb += (size_t)BATCH * NHEAD * NTOK * MDIM * 2;
  float* kgb = (float*)wsb; wsb += (size_t)BATCH * NHEAD * NTOK * MDIM * 4;
  float* vgb = (float*)wsb; wsb += (size_t)BATCH * NHEAD * NTOK * MDIM * 4;
  float* x1pre = (float*)wsb; wsb += (size_t)BATCH * NPIX * CDIM * 4;
  float* x0pre = (float*)wsb; wsb += (size_t)BATCH * CDIM * 4;
  float* bias_pk = (float*)wsb; wsb += (size_t)NHEAD * 4 * NT * 64 * 4 * 4;

  dim3 g1((BATCH * NTOK + 63) / 64, 30);
  k_qkv<<<g1, 256, 0, stream>>>(x, wq, wkv, wkvg, qb, kb, vb, kgb, vgb);

  int nbias = NHEAD * 4 * NT * 64;
  k_bias<<<(nbias + 255) / 256, 256, 0, stream>>>(lbt, g2l, rel, bias_pk);

  dim3 g2(64, BATCH * NHEAD);
  k_local<<<g2, 256, 0, stream>>>(qb, kb, vb, bias_pk, x1pre);

  k_glob<<<BATCH * NHEAD, 256, 0, stream>>>(x, wqg, kgb, vgb, g2l, g2g, x0pre);

  dim3 g4(BATCH * NPIX / 64, 6);
  k_proj<<<g4, 256, 0, stream>>>(x1pre, wproj, bproj, out);

  k_x0proj<<<BATCH, CDIM, 0, stream>>>(x0pre, wprojg, bprojg, out);
}

// Round 3
// 365.556 us; speedup vs baseline: 3.1201x; 1.5894x over previous
//
#include <hip/hip_runtime.h>
#include <hip/hip_bf16.h>
#include <math.h>

#define NHEAD 12
#define MDIM 32
#define CDIM 384
#define BATCH 4
#define NTOK 3137
#define NPIX 3136
#define NXDIM 56
#define WW 7
#define W2 49
#define NKEYP 448
#define NT 28
#define NEGV -1000000000.0f
#define QSCALE 0.17677669529663687f
#define NROWS 12548
#define NROWP 12672

typedef unsigned int u32;
typedef unsigned short u16;
typedef __attribute__((ext_vector_type(8))) short bf16x8;
typedef __attribute__((ext_vector_type(4))) float f32x4;

__device__ __forceinline__ u32 pk_bf16(float a, float b){
  u16 x = __builtin_bit_cast(u16, __float2bfloat16(a));
  u16 y = __builtin_bit_cast(u16, __float2bfloat16(b));
  return (u32)x | ((u32)y << 16);
}
__device__ __forceinline__ u16 to_bf(float a){
  return __builtin_bit_cast(u16, __float2bfloat16(a));
}

// ---------------- P1: x -> bf16 (padded rows zeroed) ----------------
__global__ __launch_bounds__(256) void k_prep_x(const float* __restrict__ x, u16* __restrict__ xb)
{
  int idx = blockIdx.x * 256 + threadIdx.x;
  const int total = NROWP * CDIM / 8;
  if (idx >= total) return;
  size_t base = (size_t)idx * 8;
  uint4 o;
  if (base < (size_t)NROWS * CDIM) {
    float4 a = *(const float4*)(x + base);
    float4 b = *(const float4*)(x + base + 4);
    o.x = pk_bf16(a.x, a.y); o.y = pk_bf16(a.z, a.w);
    o.z = pk_bf16(b.x, b.y); o.w = pk_bf16(b.z, b.w);
  } else {
    o = make_uint4(0, 0, 0, 0);
  }
  *(uint4*)(xb + base) = o;
}

// ---------------- P2: transpose+bf16 combined weights -> Wt[1920][384] ----------------
__global__ __launch_bounds__(256) void k_prep_w(
    const float* __restrict__ wq, const float* __restrict__ wkv,
    const float* __restrict__ wkvg, u16* __restrict__ Wt)
{
  __shared__ float t[64][65];
  int n0 = blockIdx.x * 64, k0 = blockIdx.y * 64;
  const float* Wp; int ld, coff;
  if (n0 < 384)       { Wp = wq;   ld = 384; coff = n0; }
  else if (n0 < 1152) { Wp = wkv;  ld = 768; coff = n0 - 384; }
  else                { Wp = wkvg; ld = 768; coff = n0 - 1152; }
  int tid = threadIdx.x;
  int nx = (tid & 15) * 4, ky = tid >> 4;
#pragma unroll
  for (int p = 0; p < 4; ++p) {
    int k = ky + p * 16;
    float4 v = *(const float4*)(Wp + (size_t)(k0 + k) * ld + coff + nx);
    t[nx + 0][k] = v.x; t[nx + 1][k] = v.y; t[nx + 2][k] = v.z; t[nx + 3][k] = v.w;
  }
  __syncthreads();
  int row = tid >> 3, seg = tid & 7;
#pragma unroll
  for (int p = 0; p < 2; ++p) {
    int n = row + p * 32;
    const float* src = &t[n][seg * 8];
    uint4 o;
    o.x = pk_bf16(src[0], src[1]); o.y = pk_bf16(src[2], src[3]);
    o.z = pk_bf16(src[4], src[5]); o.w = pk_bf16(src[6], src[7]);
    *(uint4*)(Wt + (size_t)(n0 + n) * CDIM + k0 + seg * 8) = o;
  }
}

// ---------------- K1: qkv projection via MFMA ----------------
// C[12672 x 1920] = xb @ Wt^T ; tiles 128x128, BK=64, 4 waves (2x2 of 64x64)
__global__ __launch_bounds__(256) void k_qkv_mfma(
    const u16* __restrict__ xb, const u16* __restrict__ Wt,
    u16* __restrict__ qb, u16* __restrict__ kb, u16* __restrict__ vb,
    float* __restrict__ kgb, float* __restrict__ vgb)
{
  __shared__ __align__(16) u16 As[128][72];
  __shared__ __align__(16) u16 Bs[128][72];
  int tid = threadIdx.x, lane = tid & 63, wv = tid >> 6;
  int r16 = lane & 15, g = lane >> 4;
  int tok0 = blockIdx.x * 128, n0 = blockIdx.y * 128;
  int wm = wv >> 1, wn = wv & 1;
  int srow = tid >> 3, sseg = tid & 7;
  f32x4 acc[4][4] = {};
  for (int k0 = 0; k0 < CDIM; k0 += 64) {
    __syncthreads();
#pragma unroll
    for (int p = 0; p < 4; ++p) {
      int row = srow + p * 32;
      uint4 a = *(const uint4*)(xb + (size_t)(tok0 + row) * CDIM + k0 + sseg * 8);
      *(uint4*)&As[row][sseg * 8] = a;
      uint4 b = *(const uint4*)(Wt + (size_t)(n0 + row) * CDIM + k0 + sseg * 8);
      *(uint4*)&Bs[row][sseg * 8] = b;
    }
    __syncthreads();
#pragma unroll
    for (int ks = 0; ks < 2; ++ks) {
      bf16x8 af[4], bfr[4];
#pragma unroll
      for (int i = 0; i < 4; ++i) {
        af[i]  = *(const bf16x8*)&As[wm * 64 + i * 16 + r16][ks * 32 + g * 8];
        bfr[i] = *(const bf16x8*)&Bs[wn * 64 + i * 16 + r16][ks * 32 + g * 8];
      }
#pragma unroll
      for (int i = 0; i < 4; ++i)
#pragma unroll
        for (int j = 0; j < 4; ++j)
          acc[i][j] = __builtin_amdgcn_mfma_f32_16x16x32_bf16(af[i], bfr[j], acc[i][j], 0, 0, 0);
    }
  }
  // epilogue scatter: D[tok][chan], tok = tok0+wm*64+i*16+4g+r, chan = n0+wn*64+j*16+r16
#pragma unroll
  for (int i = 0; i < 4; ++i) {
    int tokb = tok0 + wm * 64 + i * 16 + 4 * g;
#pragma unroll
    for (int j = 0; j < 4; ++j) {
      int chan = n0 + wn * 64 + j * 16 + r16;
      f32x4 v = acc[i][j];
      if (chan < 384) {
        int h = chan >> 5, d = chan & 31;
#pragma unroll
        for (int r = 0; r < 4; ++r) {
          int tok = tokb + r;
          if (tok < NROWS) {
            int b = tok / NTOK, n = tok - b * NTOK;
            if (n > 0)
              qb[(((size_t)b * NHEAD + h) * NPIX + (n - 1)) * MDIM + d] = to_bf(v[r] * QSCALE);
          }
        }
      } else if (chan < 1152) {
        int c2 = chan - 384;
        u16* dst = (c2 < 384) ? kb : vb;
        int cm = (c2 < 384) ? c2 : c2 - 384;
        int h = cm >> 5, d = cm & 31;
#pragma unroll
        for (int r = 0; r < 4; ++r) {
          int tok = tokb + r;
          if (tok < NROWS) {
            int b = tok / NTOK, n = tok - b * NTOK;
            dst[(((size_t)b * NHEAD + h) * NTOK + n) * MDIM + d] = to_bf(v[r]);
          }
        }
      } else {
        int c3 = chan - 1152;
        float* dst = (c3 < 384) ? kgb : vgb;
        int cm = (c3 < 384) ? c3 : c3 - 384;
        int h = cm >> 5, d = cm & 31;
#pragma unroll
        for (int r = 0; r < 4; ++r) {
          int tok = tokb + r;
          if (tok < NROWS) {
            int b = tok / NTOK, n = tok - b * NTOK;
            dst[(((size_t)b * NHEAD + h) * NTOK + n) * MDIM + d] = v[r];
          }
        }
      }
    }
  }
}

// ---------------- K1b: precompute bias in MFMA C-fragment layout ----------------
__global__ __launch_bounds__(256) void k_bias(
    const float* __restrict__ lbt, const float* __restrict__ g2l,
    const int* __restrict__ rel, float* __restrict__ bias_pk)
{
  int idx = blockIdx.x * 256 + threadIdx.x;
  if (idx >= NHEAD * 4 * NT * 64) return;
  int lane = idx & 63;
  int t = (idx >> 6) % NT;
  int hw = (idx >> 6) / NT;
  int w = hw & 3, h = hw >> 2;
  int g = lane >> 4;
  int q = 16 * w + (lane & 15); if (q > 48) q = 48;
  float4 v;
  float* vp = (float*)&v;
#pragma unroll
  for (int r = 0; r < 4; ++r) {
    int k = 16 * t + 4 * g + r;
    float val;
    if (k == 0) val = g2l[NHEAD + h];
    else if (k <= 441) val = lbt[rel[q * 441 + (k - 1)] * NHEAD + h];
    else val = NEGV;
    vp[r] = val;
  }
  *(float4*)(bias_pk + (size_t)idx * 4) = v;
}

// ---------------- K2: windowed local attention via MFMA ----------------
__device__ __forceinline__ int key_tok(int key, int mi, int nj, bool& valid){
  if (key == 0) { valid = true; return 0; }
  if (key > 441) { valid = false; return 0; }
  int j = key - 1, kk = j / 49, t = j - kk * 49;
  int px = mi + kk / 3 - 1, py = nj + kk % 3 - 1;
  valid = (px >= 0) && (px < 8) && (py >= 0) && (py < 8);
  return valid ? (1 + (px * WW + t / WW) * NXDIM + (py * WW + t % WW)) : 0;
}

__global__ __launch_bounds__(256) void k_local(
    const u16* __restrict__ qb, const u16* __restrict__ kb, const u16* __restrict__ vb,
    const float* __restrict__ bias_pk, float* __restrict__ x1pre)
{
  __shared__ __align__(16) u16 Ks[NKEYP * 40];
  __shared__ __align__(16) u16 Vt[32 * 456];
  __shared__ __align__(16) u16 Pbuf[4 * 640];
  __shared__ __align__(16) float Msk[NKEYP];

  int tid = threadIdx.x, lane = tid & 63, wv = tid >> 6;
  int r16 = lane & 15, g = lane >> 4;
  int bh = blockIdx.y, b = bh / NHEAD, h = bh % NHEAD;
  int wid = blockIdx.x, mi = wid >> 3, nj = wid & 7;
  const u16* kbh = kb + (size_t)bh * NTOK * MDIM;
  const u16* vbh = vb + (size_t)bh * NTOK * MDIM;
  const u16* qbh = qb + (size_t)bh * NPIX * MDIM;

  for (int i = tid; i < NKEYP * 4; i += 256) {
    int key = i >> 2, seg = i & 3;
    bool val; int n = key_tok(key, mi, nj, val);
    uint4 kv = make_uint4(0, 0, 0, 0);
    if (val) kv = *(const uint4*)(kbh + (size_t)n * MDIM + seg * 8);
    *(uint4*)&Ks[key * 40 + seg * 8] = kv;
  }
  for (int i = tid; i < 224 * 8; i += 256) {
    int kp = i >> 3, seg = i & 7;
    bool v0, v1;
    int n0 = key_tok(2 * kp, mi, nj, v0);
    int n1 = key_tok(2 * kp + 1, mi, nj, v1);
    uint2 a0 = make_uint2(0, 0), a1 = make_uint2(0, 0);
    if (v0) a0 = *(const uint2*)(vbh + (size_t)n0 * MDIM + seg * 4);
    if (v1) a1 = *(const uint2*)(vbh + (size_t)n1 * MDIM + seg * 4);
    int d0 = seg * 4;
    *(u32*)&Vt[(d0 + 0) * 456 + 2 * kp] = (a0.x & 0xffffu) | ((a1.x & 0xffffu) << 16);
    *(u32*)&Vt[(d0 + 1) * 456 + 2 * kp] = (a0.x >> 16)     | (a1.x & 0xffff0000u);
    *(u32*)&Vt[(d0 + 2) * 456 + 2 * kp] = (a0.y & 0xffffu) | ((a1.y & 0xffffu) << 16);
    *(u32*)&Vt[(d0 + 3) * 456 + 2 * kp] = (a0.y >> 16)     | (a1.y & 0xffff0000u);
  }
  for (int i = tid; i < NKEYP; i += 256) {
    float mv = NEGV;
    if (i == 0) mv = 0.f;
    else if (i <= 441) {
      int j = i - 1, kk = j / 49;
      int px = mi + kk / 3 - 1, py = nj + kk % 3 - 1;
      mv = ((px >= 0) && (px < 8) && (py >= 0) && (py < 8)) ? 0.f : NEGV;
    }
    Msk[i] = mv;
  }
  int q0 = wv * 16 + r16, qc = (q0 < 49) ? q0 : 48;
  int qpix = (mi * WW + qc / WW) * NXDIM + (nj * WW + qc % WW);
  uint4 qv = *(const uint4*)(qbh + (size_t)qpix * MDIM + 8 * g);
  bf16x8 qf = __builtin_bit_cast(bf16x8, qv);
  __syncthreads();

  f32x4 acc[NT];
  const float4* bp = (const float4*)bias_pk + ((size_t)(h * 4 + wv) * NT) * 64 + lane;
#pragma unroll
  for (int t = 0; t < NT; ++t) {
    float4 bv = bp[t * 64];
    float4 mv = *(const float4*)&Msk[t * 16 + 4 * g];
    f32x4 cin = {bv.x + mv.x, bv.y + mv.y, bv.z + mv.z, bv.w + mv.w};
    uint4 av = *(const uint4*)&Ks[(t * 16 + r16) * 40 + 8 * g];
    acc[t] = __builtin_amdgcn_mfma_f32_16x16x32_bf16(
        __builtin_bit_cast(bf16x8, av), qf, cin, 0, 0, 0);
  }
  float mx = -INFINITY;
#pragma unroll
  for (int t = 0; t < NT; ++t)
    mx = fmaxf(mx, fmaxf(fmaxf(acc[t].x, acc[t].y), fmaxf(acc[t].z, acc[t].w)));
  mx = fmaxf(mx, __shfl_xor(mx, 16));
  mx = fmaxf(mx, __shfl_xor(mx, 32));
  float ssum = 0.f;
#pragma unroll
  for (int t = 0; t < NT; ++t) {
    acc[t].x = __expf(acc[t].x - mx); ssum += acc[t].x;
    acc[t].y = __expf(acc[t].y - mx); ssum += acc[t].y;
    acc[t].z = __expf(acc[t].z - mx); ssum += acc[t].z;
    acc[t].w = __expf(acc[t].w - mx); ssum += acc[t].w;
  }
  ssum += __shfl_xor(ssum, 16);
  ssum += __shfl_xor(ssum, 32);

  f32x4 o0 = {0.f, 0.f, 0.f, 0.f}, o1 = {0.f, 0.f, 0.f, 0.f};
  u16* Pb = Pbuf + wv * 640;
#pragma unroll
  for (int c = 0; c < 14; ++c) {
    f32x4 p0 = acc[2 * c], p1 = acc[2 * c + 1];
    *(u32*)&Pb[r16 * 40 + 4 * g]          = pk_bf16(p0.x, p0.y);
    *(u32*)&Pb[r16 * 40 + 4 * g + 2]      = pk_bf16(p0.z, p0.w);
    *(u32*)&Pb[r16 * 40 + 16 + 4 * g]     = pk_bf16(p1.x, p1.y);
    *(u32*)&Pb[r16 * 40 + 16 + 4 * g + 2] = pk_bf16(p1.z, p1.w);
    uint4 pv = *(uint4*)&Pb[r16 * 40 + 8 * g];
    uint4 v0 = *(const uint4*)&Vt[r16 * 456 + 32 * c + 8 * g];
    uint4 v1 = *(const uint4*)&Vt[(16 + r16) * 456 + 32 * c + 8 * g];
    o0 = __builtin_amdgcn_mfma_f32_16x16x32_bf16(
        __builtin_bit_cast(bf16x8, v0), __builtin_bit_cast(bf16x8, pv), o0, 0, 0, 0);
    o1 = __builtin_amdgcn_mfma_f32_16x16x32_bf16(
        __builtin_bit_cast(bf16x8, v1), __builtin_bit_cast(bf16x8, pv), o1, 0, 0, 0);
  }
  if (q0 < 49) {
    float inv = 1.f / ssum;
    float* op = x1pre + ((size_t)b * NPIX + qpix) * CDIM + h * MDIM;
    op[4 * g + 0] = o0.x * inv; op[4 * g + 1] = o0.y * inv;
    op[4 * g + 2] = o0.z * inv; op[4 * g + 3] = o0.w * inv;
    op[16 + 4 * g + 0] = o1.x * inv; op[16 + 4 * g + 1] = o1.y * inv;
    op[16 + 4 * g + 2] = o1.z * inv; op[16 + 4 * g + 3] = o1.w * inv;
  }
}

// ---------------- K3: global token attention ----------------
__global__ __launch_bounds__(256) void k_glob(
    const float* __restrict__ x, const float* __restrict__ wqg,
    const float* __restrict__ kgb, const float* __restrict__ vgb,
    const float* __restrict__ g2l, const float* __restrict__ g2g,
    float* __restrict__ x0pre)
{
  int bh = blockIdx.x, b = bh / NHEAD, h = bh % NHEAD;
  __shared__ float qg[32];
  __shared__ float lg[NTOK];
  __shared__ float red[4];
  __shared__ float accw[4][32];
  __shared__ float sw[4];
  int tid = threadIdx.x, wv = tid >> 6;
  const float* xr = x + (size_t)b * NTOK * CDIM;
  if (tid < 32) {
    float a = 0.f;
    for (int kk = 0; kk < CDIM; ++kk) a += xr[kk] * wqg[(size_t)kk * CDIM + h * MDIM + tid];
    qg[tid] = a * QSCALE;
  }
  __syncthreads();
  const float* kbh = kgb + (size_t)bh * NTOK * MDIM;
  const float* vbh = vgb + (size_t)bh * NTOK * MDIM;
  float b0 = g2g[h], b1 = g2l[h];
  float lmax = -INFINITY;
  for (int n = tid; n < NTOK; n += 256) {
    const float4* kr = (const float4*)(kbh + (size_t)n * MDIM);
    float dot = 0.f;
#pragma unroll
    for (int gg = 0; gg < 8; ++gg) {
      float4 t4 = kr[gg];
      dot += qg[4*gg]*t4.x + qg[4*gg+1]*t4.y + qg[4*gg+2]*t4.z + qg[4*gg+3]*t4.w;
    }
    dot += (n == 0) ? b0 : b1;
    lg[n] = dot;
    lmax = fmaxf(lmax, dot);
  }
#pragma unroll
  for (int off = 32; off; off >>= 1) lmax = fmaxf(lmax, __shfl_down(lmax, off));
  if ((tid & 63) == 0) red[wv] = lmax;
  __syncthreads();
  float M = fmaxf(fmaxf(red[0], red[1]), fmaxf(red[2], red[3]));
  float s = 0.f, acc[32] = {};
  for (int n = tid; n < NTOK; n += 256) {
    float p = __expf(lg[n] - M);
    s += p;
    const float4* vr = (const float4*)(vbh + (size_t)n * MDIM);
#pragma unroll
    for (int gg = 0; gg < 8; ++gg) {
      float4 t4 = vr[gg];
      acc[4*gg]   += p * t4.x; acc[4*gg+1] += p * t4.y;
      acc[4*gg+2] += p * t4.z; acc[4*gg+3] += p * t4.w;
    }
  }
#pragma unroll
  for (int off = 32; off; off >>= 1) {
    s += __shfl_down(s, off);
#pragma unroll
    for (int d = 0; d < 32; ++d) acc[d] += __shfl_down(acc[d], off);
  }
  if ((tid & 63) == 0) {
    sw[wv] = s;
#pragma unroll
    for (int d = 0; d < 32; ++d) accw[wv][d] = acc[d];
  }
  __syncthreads();
  if (tid < 32) {
    float S = sw[0] + sw[1] + sw[2] + sw[3];
    float o = accw[0][tid] + accw[1][tid] + accw[2][tid] + accw[3][tid];
    x0pre[(size_t)b * CDIM + h * MDIM + tid] = o / S;
  }
}

// ---------------- K4: x1 output projection (fp32, unchanged) ----------------
__global__ __launch_bounds__(256) void k_proj(
    const float* __restrict__ a, const float* __restrict__ wproj,
    const float* __restrict__ bproj, float* __restrict__ out)
{
  __shared__ float As[16][64];
  __shared__ float Bs[16][64];
  int row0 = blockIdx.x * 64, col0 = blockIdx.y * 64;
  int tid = threadIdx.x, tx = tid & 15, ty = tid >> 4;
  int lr = tid >> 2, lk = (tid & 3) * 4;
  int bk = tid >> 4, bc = (tid & 15) * 4;
  float acc[4][4] = {};
  for (int k0 = 0; k0 < CDIM; k0 += 16) {
    float4 av = *(const float4*)(a + (size_t)(row0 + lr) * CDIM + k0 + lk);
    float4 bv = *(const float4*)(wproj + (size_t)(k0 + bk) * CDIM + col0 + bc);
    As[lk + 0][lr] = av.x; As[lk + 1][lr] = av.y;
    As[lk + 2][lr] = av.z; As[lk + 3][lr] = av.w;
    *(float4*)&Bs[bk][bc] = bv;
    __syncthreads();
#pragma unroll
    for (int kk = 0; kk < 16; ++kk) {
      float4 a4 = *(const float4*)&As[kk][ty * 4];
      float4 b4 = *(const float4*)&Bs[kk][tx * 4];
      float av2[4] = {a4.x, a4.y, a4.z, a4.w};
      float bv2[4] = {b4.x, b4.y, b4.z, b4.w};
#pragma unroll
      for (int i = 0; i < 4; ++i)
#pragma unroll
        for (int j = 0; j < 4; ++j) acc[i][j] += av2[i] * bv2[j];
    }
    __syncthreads();
  }
#pragma unroll
  for (int i = 0; i < 4; ++i) {
    int r = row0 + ty * 4 + i;
    int b = r / NPIX, p = r % NPIX;
#pragma unroll
    for (int j = 0; j < 4; ++j) {
      int c = col0 + tx * 4 + j;
      out[((size_t)b * NTOK + 1 + p) * CDIM + c] = acc[i][j] + bproj[c];
    }
  }
}

// ---------------- K5: x0 output projection (tiny) ----------------
__global__ void k_x0proj(const float* __restrict__ x0pre, const float* __restrict__ wprojg,
                         const float* __restrict__ bprojg, float* __restrict__ out)
{
  int b = blockIdx.x, c = threadIdx.x;
  __shared__ float xr[CDIM];
  xr[c] = x0pre[(size_t)b * CDIM + c];
  __syncthreads();
  float acc = bprojg[c];
  for (int kk = 0; kk < CDIM; ++kk) acc += xr[kk] * wprojg[(size_t)kk * CDIM + c];
  out[(size_t)b * NTOK * CDIM + c] = acc;
}

extern "C" void kernel_launch(void* const* d_in, const int* in_sizes, int n_in,
                              void* d_out, int out_size, void* d_ws, size_t ws_size,
                              hipStream_t stream)
{
  const float* x      = (const float*)d_in[0];
  const float* wq     = (const float*)d_in[1];
  const float* wkv    = (const float*)d_in[2];
  const float* wproj  = (const float*)d_in[3];
  const float* bproj  = (const float*)d_in[4];
  const float* wqg    = (const float*)d_in[5];
  const float* wkvg   = (const float*)d_in[6];
  const float* wprojg = (const float*)d_in[7];
  const float* bprojg = (const float*)d_in[8];
  const float* lbt    = (const float*)d_in[9];
  const float* g2l    = (const float*)d_in[10];
  const float* g2g    = (const float*)d_in[11];
  const int*   rel    = (const int*)d_in[12];
  float* out = (float*)d_out;

  char* wsb = (char*)d_ws;
  u16* qb = (u16*)wsb;      wsb += (size_t)BATCH * NHEAD * NPIX * MDIM * 2;
  u16* kb = (u16*)wsb;      wsb += (size_t)BATCH * NHEAD * NTOK * MDIM * 2;
  u16* vb = (u16*)wsb;      wsb += (size_t)BATCH * NHEAD * NTOK * MDIM * 2;
  float* kgb = (float*)wsb; wsb += (size_t)BATCH * NHEAD * NTOK * MDIM * 4;
  float* vgb = (float*)wsb; wsb += (size_t)BATCH * NHEAD * NTOK * MDIM * 4;
  float* x1pre = (float*)wsb; wsb += (size_t)BATCH * NPIX * CDIM * 4;
  float* x0pre = (float*)wsb; wsb += (size_t)BATCH * CDIM * 4;
  float* bias_pk = (float*)wsb; wsb += (size_t)NHEAD * 4 * NT * 64 * 4 * 4;
  u16* xb = (u16*)wsb;      wsb += (size_t)NROWP * CDIM * 2;
  u16* Wt = (u16*)wsb;      wsb += (size_t)1920 * CDIM * 2;

  k_prep_x<<<(NROWP * CDIM / 8 + 255) / 256, 256, 0, stream>>>(x, xb);
  dim3 gw(30, 6);
  k_prep_w<<<gw, 256, 0, stream>>>(wq, wkv, wkvg, Wt);

  dim3 g1(NROWP / 128, 1920 / 128);
  k_qkv_mfma<<<g1, 256, 0, stream>>>(xb, Wt, qb, kb, vb, kgb, vgb);

  int nbias = NHEAD * 4 * NT * 64;
  k_bias<<<(nbias + 255) / 256, 256, 0, stream>>>(lbt, g2l, rel, bias_pk);

  dim3 g2(64, BATCH * NHEAD);
  k_local<<<g2, 256, 0, stream>>>(qb, kb, vb, bias_pk, x1pre);

  k_glob<<<BATCH * NHEAD, 256, 0, stream>>>(x, wqg, kgb, vgb, g2l, g2g, x0pre);

  dim3 g4(BATCH * NPIX / 64, 6);
  k_proj<<<g4, 256, 0, stream>>>(x1pre, wproj, bproj, out);

  k_x0proj<<<BATCH, CDIM, 0, stream>>>(x0pre, wprojg, bprojg, out);
}

// Round 4
// 230.308 us; speedup vs baseline: 4.9523x; 1.5872x over previous
//
#include <hip/hip_runtime.h>
#include <hip/hip_bf16.h>
#include <math.h>

#define NHEAD 12
#define MDIM 32
#define CDIM 384
#define BATCH 4
#define NTOK 3137
#define NPIX 3136
#define NXDIM 56
#define WW 7
#define W2 49
#define NKEYP 448
#define NT 28
#define NEGV -1000000000.0f
#define QSCALE 0.17677669529663687f
#define NROWS 12548
#define NROWP 12672

typedef unsigned int u32;
typedef unsigned short u16;
typedef __attribute__((ext_vector_type(8))) short bf16x8;
typedef __attribute__((ext_vector_type(4))) float f32x4;

__device__ __forceinline__ u32 pk_bf16(float a, float b){
  u16 x = __builtin_bit_cast(u16, __float2bfloat16(a));
  u16 y = __builtin_bit_cast(u16, __float2bfloat16(b));
  return (u32)x | ((u32)y << 16);
}
__device__ __forceinline__ u16 to_bf(float a){
  return __builtin_bit_cast(u16, __float2bfloat16(a));
}
__device__ __forceinline__ float bf_rt(float a){   // bf16 round-trip
  return __bfloat162float(__float2bfloat16(a));
}

// ---------------- P1: x -> bf16 (padded rows zeroed) ----------------
__global__ __launch_bounds__(256) void k_prep_x(const float* __restrict__ x, u16* __restrict__ xb)
{
  int idx = blockIdx.x * 256 + threadIdx.x;
  const int total = NROWP * CDIM / 8;
  if (idx >= total) return;
  size_t base = (size_t)idx * 8;
  uint4 o;
  if (base < (size_t)NROWS * CDIM) {
    float4 a = *(const float4*)(x + base);
    float4 b = *(const float4*)(x + base + 4);
    o.x = pk_bf16(a.x, a.y); o.y = pk_bf16(a.z, a.w);
    o.z = pk_bf16(b.x, b.y); o.w = pk_bf16(b.z, b.w);
  } else {
    o = make_uint4(0, 0, 0, 0);
  }
  *(uint4*)(xb + base) = o;
}

// ---------------- P2: transpose+bf16 combined qkv weights -> Wt[1920][384] ----------------
__global__ __launch_bounds__(256) void k_prep_w(
    const float* __restrict__ wq, const float* __restrict__ wkv,
    const float* __restrict__ wkvg, u16* __restrict__ Wt)
{
  __shared__ float t[64][65];
  int n0 = blockIdx.x * 64, k0 = blockIdx.y * 64;
  const float* Wp; int ld, coff;
  if (n0 < 384)       { Wp = wq;   ld = 384; coff = n0; }
  else if (n0 < 1152) { Wp = wkv;  ld = 768; coff = n0 - 384; }
  else                { Wp = wkvg; ld = 768; coff = n0 - 1152; }
  int tid = threadIdx.x;
  int nx = (tid & 15) * 4, ky = tid >> 4;
#pragma unroll
  for (int p = 0; p < 4; ++p) {
    int k = ky + p * 16;
    float4 v = *(const float4*)(Wp + (size_t)(k0 + k) * ld + coff + nx);
    t[nx + 0][k] = v.x; t[nx + 1][k] = v.y; t[nx + 2][k] = v.z; t[nx + 3][k] = v.w;
  }
  __syncthreads();
  int row = tid >> 3, seg = tid & 7;
#pragma unroll
  for (int p = 0; p < 2; ++p) {
    int n = row + p * 32;
    const float* src = &t[n][seg * 8];
    uint4 o;
    o.x = pk_bf16(src[0], src[1]); o.y = pk_bf16(src[2], src[3]);
    o.z = pk_bf16(src[4], src[5]); o.w = pk_bf16(src[6], src[7]);
    *(uint4*)(Wt + (size_t)(n0 + n) * CDIM + k0 + seg * 8) = o;
  }
}

// ---------------- P3: transpose wproj -> hi/lo bf16 [col][k] ----------------
__global__ __launch_bounds__(256) void k_prep_wp(
    const float* __restrict__ wproj, u16* __restrict__ wph, u16* __restrict__ wpl)
{
  __shared__ float t[64][65];
  int c0 = blockIdx.x * 64, k0 = blockIdx.y * 64;
  int tid = threadIdx.x;
  int cx = (tid & 15) * 4, ky = tid >> 4;
#pragma unroll
  for (int p = 0; p < 4; ++p) {
    int k = ky + p * 16;
    float4 v = *(const float4*)(wproj + (size_t)(k0 + k) * CDIM + c0 + cx);
    t[cx + 0][k] = v.x; t[cx + 1][k] = v.y; t[cx + 2][k] = v.z; t[cx + 3][k] = v.w;
  }
  __syncthreads();
  int row = tid >> 3, seg = tid & 7;
#pragma unroll
  for (int p = 0; p < 2; ++p) {
    int c = row + p * 32;
    const float* src = &t[c][seg * 8];
    u32 hw[4], lw[4];
#pragma unroll
    for (int q = 0; q < 4; ++q) {
      float v0 = src[2 * q], v1 = src[2 * q + 1];
      u16 h0 = to_bf(v0), h1 = to_bf(v1);
      float l0 = v0 - __bfloat162float(__builtin_bit_cast(__hip_bfloat16, h0));
      float l1 = v1 - __bfloat162float(__builtin_bit_cast(__hip_bfloat16, h1));
      hw[q] = (u32)h0 | ((u32)h1 << 16);
      lw[q] = pk_bf16(l0, l1);
    }
    *(uint4*)(wph + (size_t)(c0 + c) * CDIM + k0 + seg * 8) = make_uint4(hw[0], hw[1], hw[2], hw[3]);
    *(uint4*)(wpl + (size_t)(c0 + c) * CDIM + k0 + seg * 8) = make_uint4(lw[0], lw[1], lw[2], lw[3]);
  }
}

// ---------------- K1: qkv projection via MFMA ----------------
__global__ __launch_bounds__(256) void k_qkv_mfma(
    const u16* __restrict__ xb, const u16* __restrict__ Wt,
    u16* __restrict__ qb, u16* __restrict__ kb, u16* __restrict__ vb,
    float* __restrict__ kgb, float* __restrict__ vgb)
{
  __shared__ __align__(16) u16 As[128][72];
  __shared__ __align__(16) u16 Bs[128][72];
  int tid = threadIdx.x, lane = tid & 63, wv = tid >> 6;
  int r16 = lane & 15, g = lane >> 4;
  int tok0 = blockIdx.x * 128, n0 = blockIdx.y * 128;
  int wm = wv >> 1, wn = wv & 1;
  int srow = tid >> 3, sseg = tid & 7;
  f32x4 acc[4][4] = {};
  for (int k0 = 0; k0 < CDIM; k0 += 64) {
    __syncthreads();
#pragma unroll
    for (int p = 0; p < 4; ++p) {
      int row = srow + p * 32;
      uint4 a = *(const uint4*)(xb + (size_t)(tok0 + row) * CDIM + k0 + sseg * 8);
      *(uint4*)&As[row][sseg * 8] = a;
      uint4 b = *(const uint4*)(Wt + (size_t)(n0 + row) * CDIM + k0 + sseg * 8);
      *(uint4*)&Bs[row][sseg * 8] = b;
    }
    __syncthreads();
#pragma unroll
    for (int ks = 0; ks < 2; ++ks) {
      bf16x8 af[4], bfr[4];
#pragma unroll
      for (int i = 0; i < 4; ++i) {
        af[i]  = *(const bf16x8*)&As[wm * 64 + i * 16 + r16][ks * 32 + g * 8];
        bfr[i] = *(const bf16x8*)&Bs[wn * 64 + i * 16 + r16][ks * 32 + g * 8];
      }
#pragma unroll
      for (int i = 0; i < 4; ++i)
#pragma unroll
        for (int j = 0; j < 4; ++j)
          acc[i][j] = __builtin_amdgcn_mfma_f32_16x16x32_bf16(af[i], bfr[j], acc[i][j], 0, 0, 0);
    }
  }
#pragma unroll
  for (int i = 0; i < 4; ++i) {
    int tokb = tok0 + wm * 64 + i * 16 + 4 * g;
#pragma unroll
    for (int j = 0; j < 4; ++j) {
      int chan = n0 + wn * 64 + j * 16 + r16;
      f32x4 v = acc[i][j];
      if (chan < 384) {
        int h = chan >> 5, d = chan & 31;
#pragma unroll
        for (int r = 0; r < 4; ++r) {
          int tok = tokb + r;
          if (tok < NROWS) {
            int b = tok / NTOK, n = tok - b * NTOK;
            if (n > 0)
              qb[(((size_t)b * NHEAD + h) * NPIX + (n - 1)) * MDIM + d] = to_bf(v[r] * QSCALE);
          }
        }
      } else if (chan < 1152) {
        int c2 = chan - 384;
        u16* dst = (c2 < 384) ? kb : vb;
        int cm = (c2 < 384) ? c2 : c2 - 384;
        int h = cm >> 5, d = cm & 31;
#pragma unroll
        for (int r = 0; r < 4; ++r) {
          int tok = tokb + r;
          if (tok < NROWS) {
            int b = tok / NTOK, n = tok - b * NTOK;
            dst[(((size_t)b * NHEAD + h) * NTOK + n) * MDIM + d] = to_bf(v[r]);
          }
        }
      } else {
        int c3 = chan - 1152;
        float* dst = (c3 < 384) ? kgb : vgb;
        int cm = (c3 < 384) ? c3 : c3 - 384;
        int h = cm >> 5, d = cm & 31;
#pragma unroll
        for (int r = 0; r < 4; ++r) {
          int tok = tokb + r;
          if (tok < NROWS) {
            int b = tok / NTOK, n = tok - b * NTOK;
            dst[(((size_t)b * NHEAD + h) * NTOK + n) * MDIM + d] = v[r];
          }
        }
      }
    }
  }
}

// ---------------- P4: per-window key->token tables + masks ----------------
__device__ __forceinline__ int key_tok(int key, int mi, int nj, bool& valid){
  if (key == 0) { valid = true; return 0; }
  if (key > 441) { valid = false; return 0; }
  int j = key - 1, kk = j / 49, t = j - kk * 49;
  int px = mi + kk / 3 - 1, py = nj + kk % 3 - 1;
  valid = (px >= 0) && (px < 8) && (py >= 0) && (py < 8);
  return valid ? (1 + (px * WW + t / WW) * NXDIM + (py * WW + t % WW)) : 0;
}

__global__ __launch_bounds__(256) void k_winprep(
    int* __restrict__ ktokA, int* __restrict__ ktokL, float* __restrict__ mskf)
{
  int idx = blockIdx.x * 256 + threadIdx.x;
  if (idx >= 64 * NKEYP) return;
  int wid = idx / NKEYP, key = idx - wid * NKEYP;
  int mi = wid >> 3, nj = wid & 7;
  bool valid; int n = key_tok(key, mi, nj, valid);
  int tok = valid ? n : 0;
  ktokL[idx] = tok;
  int t = key >> 4, r = key & 15;
  ktokA[wid * NKEYP + r * NT + t] = tok;
  mskf[idx] = valid ? 0.f : NEGV;
}

// ---------------- K1b: bias in MFMA C-fragment layout ----------------
__global__ __launch_bounds__(256) void k_bias(
    const float* __restrict__ lbt, const float* __restrict__ g2l,
    const int* __restrict__ rel, float* __restrict__ bias_pk)
{
  int idx = blockIdx.x * 256 + threadIdx.x;
  if (idx >= NHEAD * 4 * NT * 64) return;
  int lane = idx & 63;
  int t = (idx >> 6) % NT;
  int hw = (idx >> 6) / NT;
  int w = hw & 3, h = hw >> 2;
  int g = lane >> 4;
  int q = 16 * w + (lane & 15); if (q > 48) q = 48;
  float4 v;
  float* vp = (float*)&v;
#pragma unroll
  for (int r = 0; r < 4; ++r) {
    int k = 16 * t + 4 * g + r;
    float val;
    if (k == 0) val = g2l[NHEAD + h];
    else if (k <= 441) val = lbt[rel[q * 441 + (k - 1)] * NHEAD + h];
    else val = NEGV;
    vp[r] = val;
  }
  *(float4*)(bias_pk + (size_t)idx * 4) = v;
}

// ---------------- K2: windowed local attention (flash-style MFMA) ----------------
// grid: (64 windows, B*H), 4 waves; wave wv owns queries 16wv..16wv+15.
__global__ __launch_bounds__(256, 4) void k_local(
    const u16* __restrict__ qb, const u16* __restrict__ kb, const u16* __restrict__ vb,
    const float* __restrict__ bias_pk, const int* __restrict__ ktokA,
    const int* __restrict__ ktokL, const float* __restrict__ mskf,
    u16* __restrict__ x1h, u16* __restrict__ x1l)
{
  __shared__ __align__(16) u16 Vt[32][456];   // V^T, columns permuted (29184 B)

  int tid = threadIdx.x, lane = tid & 63, wv = tid >> 6;
  int r16 = lane & 15, g = lane >> 4;
  int bh = blockIdx.y, b = bh / NHEAD, h = bh % NHEAD;
  int wid = blockIdx.x, mi = wid >> 3, nj = wid & 7;
  const u16* kbh = kb + (size_t)bh * NTOK * MDIM;
  const u16* vbh = vb + (size_t)bh * NTOK * MDIM;
  const u16* qbh = qb + (size_t)bh * NPIX * MDIM;
  const int* tA = ktokA + wid * NKEYP;
  const int* tL = ktokL + wid * NKEYP;
  const float* mw = mskf + wid * NKEYP;

  // --- stage V^T with permuted columns: col = (key&~31) | (g'<<3) | (t'<<2) | r ---
  {
    int l15 = lane & 15, lg = lane >> 4;
#pragma unroll
    for (int u = wv; u < 28; u += 4) {
      int dq = u & 1, it = u >> 1;
      int kp = it * 16 + l15;               // key-pair 0..223
      int d0 = dq * 16 + lg * 4;
      int key0 = 2 * kp;
      int t0_ = tL[key0], t1_ = tL[key0 + 1];
      uint2 a0 = *(const uint2*)(vbh + (size_t)t0_ * MDIM + d0);
      uint2 a1 = *(const uint2*)(vbh + (size_t)t1_ * MDIM + d0);
      int w = key0 & 31;
      int col = (key0 & ~31) | (((w >> 2) & 3) << 3) | ((w >> 4) << 2) | (w & 3);
      *(u32*)&Vt[d0 + 0][col] = (a0.x & 0xffffu) | (a1.x << 16);
      *(u32*)&Vt[d0 + 1][col] = (a0.x >> 16)     | (a1.x & 0xffff0000u);
      *(u32*)&Vt[d0 + 2][col] = (a0.y & 0xffffu) | (a1.y << 16);
      *(u32*)&Vt[d0 + 3][col] = (a0.y >> 16)     | (a1.y & 0xffff0000u);
    }
  }

  // --- Q fragment ---
  int q0 = wv * 16 + r16, qc = (q0 < W2) ? q0 : 48;
  int qpix = (mi * WW + qc / WW) * NXDIM + (nj * WW + qc % WW);
  uint4 qv = *(const uint4*)(qbh + (size_t)qpix * MDIM + 8 * g);
  bf16x8 qf = __builtin_bit_cast(bf16x8, qv);

  // --- preload A-tokens (28, tiles for this lane's key-row r16) ---
  int4 ta[7];
#pragma unroll
  for (int i = 0; i < 7; ++i) ta[i] = *(const int4*)(tA + r16 * NT + 4 * i);

  __syncthreads();

  const float* bp = bias_pk + (size_t)(h * 4 + wv) * NT * 256 + lane * 4;
  f32x4 o0 = {0.f, 0.f, 0.f, 0.f}, o1 = {0.f, 0.f, 0.f, 0.f};
  float m = -INFINITY, ssum = 0.f;

#pragma unroll
  for (int c = 0; c < 14; ++c) {
    int t0 = 2 * c, t1 = t0 + 1;
    int4 tv = ta[c >> 1];
    int tokA0 = (c & 1) ? tv.z : tv.x;
    int tokA1 = (c & 1) ? tv.w : tv.y;
    uint4 ku0 = *(const uint4*)(kbh + (size_t)tokA0 * MDIM + 8 * g);
    uint4 ku1 = *(const uint4*)(kbh + (size_t)tokA1 * MDIM + 8 * g);
    float4 b0 = *(const float4*)(bp + t0 * 256);
    float4 b1 = *(const float4*)(bp + t1 * 256);
    float4 m0 = *(const float4*)(mw + t0 * 16 + 4 * g);
    float4 m1 = *(const float4*)(mw + t1 * 16 + 4 * g);
    f32x4 c0 = {b0.x + m0.x, b0.y + m0.y, b0.z + m0.z, b0.w + m0.w};
    f32x4 c1 = {b1.x + m1.x, b1.y + m1.y, b1.z + m1.z, b1.w + m1.w};
    f32x4 a0 = __builtin_amdgcn_mfma_f32_16x16x32_bf16(
        __builtin_bit_cast(bf16x8, ku0), qf, c0, 0, 0, 0);
    f32x4 a1 = __builtin_amdgcn_mfma_f32_16x16x32_bf16(
        __builtin_bit_cast(bf16x8, ku1), qf, c1, 0, 0, 0);
    // chunk max across this lane's 8 + across g-groups
    float cm = fmaxf(fmaxf(fmaxf(a0.x, a0.y), fmaxf(a0.z, a0.w)),
                     fmaxf(fmaxf(a1.x, a1.y), fmaxf(a1.z, a1.w)));
    cm = fmaxf(cm, __shfl_xor(cm, 16));
    cm = fmaxf(cm, __shfl_xor(cm, 32));
    float nm = fmaxf(m, cm);
    float sc = __expf(m - nm);
    m = nm;
    ssum *= sc;
    o0 *= sc; o1 *= sc;
    f32x4 e0, e1;
    e0.x = __expf(a0.x - m); e0.y = __expf(a0.y - m);
    e0.z = __expf(a0.z - m); e0.w = __expf(a0.w - m);
    e1.x = __expf(a1.x - m); e1.y = __expf(a1.y - m);
    e1.z = __expf(a1.z - m); e1.w = __expf(a1.w - m);
    ssum += (e0.x + e0.y) + (e0.z + e0.w) + (e1.x + e1.y) + (e1.z + e1.w);
    uint4 pv;
    pv.x = pk_bf16(e0.x, e0.y); pv.y = pk_bf16(e0.z, e0.w);
    pv.z = pk_bf16(e1.x, e1.y); pv.w = pk_bf16(e1.z, e1.w);
    uint4 v0 = *(const uint4*)&Vt[r16][32 * c + 8 * g];
    uint4 v1 = *(const uint4*)&Vt[16 + r16][32 * c + 8 * g];
    o0 = __builtin_amdgcn_mfma_f32_16x16x32_bf16(
        __builtin_bit_cast(bf16x8, v0), __builtin_bit_cast(bf16x8, pv), o0, 0, 0, 0);
    o1 = __builtin_amdgcn_mfma_f32_16x16x32_bf16(
        __builtin_bit_cast(bf16x8, v1), __builtin_bit_cast(bf16x8, pv), o1, 0, 0, 0);
  }
  ssum += __shfl_xor(ssum, 16);
  ssum += __shfl_xor(ssum, 32);

  if (q0 < W2) {
    float inv = 1.f / ssum;
    size_t base = ((size_t)b * NPIX + qpix) * CDIM + h * MDIM;
    float f0 = o0.x * inv, f1 = o0.y * inv, f2 = o0.z * inv, f3 = o0.w * inv;
    float g0 = o1.x * inv, g1 = o1.y * inv, g2 = o1.z * inv, g3 = o1.w * inv;
    uint2 hw0 = make_uint2(pk_bf16(f0, f1), pk_bf16(f2, f3));
    uint2 hw1 = make_uint2(pk_bf16(g0, g1), pk_bf16(g2, g3));
    *(uint2*)&x1h[base + 4 * g]      = hw0;
    *(uint2*)&x1h[base + 16 + 4 * g] = hw1;
    uint2 lw0 = make_uint2(pk_bf16(f0 - bf_rt(f0), f1 - bf_rt(f1)),
                           pk_bf16(f2 - bf_rt(f2), f3 - bf_rt(f3)));
    uint2 lw1 = make_uint2(pk_bf16(g0 - bf_rt(g0), g1 - bf_rt(g1)),
                           pk_bf16(g2 - bf_rt(g2), g3 - bf_rt(g3)));
    *(uint2*)&x1l[base + 4 * g]      = lw0;
    *(uint2*)&x1l[base + 16 + 4 * g] = lw1;
  }
}

// ---------------- K3: global token attention ----------------
__global__ __launch_bounds__(256) void k_glob(
    const float* __restrict__ x, const float* __restrict__ wqg,
    const float* __restrict__ kgb, const float* __restrict__ vgb,
    const float* __restrict__ g2l, const float* __restrict__ g2g,
    float* __restrict__ x0pre)
{
  int bh = blockIdx.x, b = bh / NHEAD, h = bh % NHEAD;
  __shared__ float qg[32];
  __shared__ float lg[NTOK];
  __shared__ float red[4];
  __shared__ float accw[4][32];
  __shared__ float sw[4];
  int tid = threadIdx.x, wv = tid >> 6;
  const float* xr = x + (size_t)b * NTOK * CDIM;
  if (tid < 32) {
    float a = 0.f;
    for (int kk = 0; kk < CDIM; ++kk) a += xr[kk] * wqg[(size_t)kk * CDIM + h * MDIM + tid];
    qg[tid] = a * QSCALE;
  }
  __syncthreads();
  const float* kbh = kgb + (size_t)bh * NTOK * MDIM;
  const float* vbh = vgb + (size_t)bh * NTOK * MDIM;
  float b0 = g2g[h], b1 = g2l[h];
  float lmax = -INFINITY;
  for (int n = tid; n < NTOK; n += 256) {
    const float4* kr = (const float4*)(kbh + (size_t)n * MDIM);
    float dot = 0.f;
#pragma unroll
    for (int gg = 0; gg < 8; ++gg) {
      float4 t4 = kr[gg];
      dot += qg[4*gg]*t4.x + qg[4*gg+1]*t4.y + qg[4*gg+2]*t4.z + qg[4*gg+3]*t4.w;
    }
    dot += (n == 0) ? b0 : b1;
    lg[n] = dot;
    lmax = fmaxf(lmax, dot);
  }
#pragma unroll
  for (int off = 32; off; off >>= 1) lmax = fmaxf(lmax, __shfl_down(lmax, off));
  if ((tid & 63) == 0) red[wv] = lmax;
  __syncthreads();
  float M = fmaxf(fmaxf(red[0], red[1]), fmaxf(red[2], red[3]));
  float s = 0.f, acc[32] = {};
  for (int n = tid; n < NTOK; n += 256) {
    float p = __expf(lg[n] - M);
    s += p;
    const float4* vr = (const float4*)(vbh + (size_t)n * MDIM);
#pragma unroll
    for (int gg = 0; gg < 8; ++gg) {
      float4 t4 = vr[gg];
      acc[4*gg]   += p * t4.x; acc[4*gg+1] += p * t4.y;
      acc[4*gg+2] += p * t4.z; acc[4*gg+3] += p * t4.w;
    }
  }
#pragma unroll
  for (int off = 32; off; off >>= 1) {
    s += __shfl_down(s, off);
#pragma unroll
    for (int d = 0; d < 32; ++d) acc[d] += __shfl_down(acc[d], off);
  }
  if ((tid & 63) == 0) {
    sw[wv] = s;
#pragma unroll
    for (int d = 0; d < 32; ++d) accw[wv][d] = acc[d];
  }
  __syncthreads();
  if (tid < 32) {
    float S = sw[0] + sw[1] + sw[2] + sw[3];
    float o = accw[0][tid] + accw[1][tid] + accw[2][tid] + accw[3][tid];
    x0pre[(size_t)b * CDIM + h * MDIM + tid] = o / S;
  }
}

// ---------------- K4: x1 projection via split-bf16 MFMA ----------------
// out = (Ah+Al) @ (Wh+Wl)^T + b, dropping Al*Wl.  A:[12544][384], W^T:[384col][384k]
__global__ __launch_bounds__(256) void k_proj_mfma(
    const u16* __restrict__ x1h, const u16* __restrict__ x1l,
    const u16* __restrict__ wph, const u16* __restrict__ wpl,
    const float* __restrict__ bproj, float* __restrict__ out)
{
  __shared__ __align__(16) u16 Ah[128][72];
  __shared__ __align__(16) u16 Al[128][72];
  __shared__ __align__(16) u16 Bh[128][72];
  __shared__ __align__(16) u16 Bl[128][72];
  int tid = threadIdx.x, lane = tid & 63, wv = tid >> 6;
  int r16 = lane & 15, g = lane >> 4;
  int row0 = blockIdx.x * 128, n0 = blockIdx.y * 128;
  int wm = wv >> 1, wn = wv & 1;
  int srow = tid >> 3, sseg = tid & 7;
  f32x4 acc[4][4] = {};
  for (int k0 = 0; k0 < CDIM; k0 += 64) {
    __syncthreads();
#pragma unroll
    for (int p = 0; p < 4; ++p) {
      int row = srow + p * 32;
      *(uint4*)&Ah[row][sseg * 8] = *(const uint4*)(x1h + (size_t)(row0 + row) * CDIM + k0 + sseg * 8);
      *(uint4*)&Al[row][sseg * 8] = *(const uint4*)(x1l + (size_t)(row0 + row) * CDIM + k0 + sseg * 8);
      *(uint4*)&Bh[row][sseg * 8] = *(const uint4*)(wph + (size_t)(n0 + row) * CDIM + k0 + sseg * 8);
      *(uint4*)&Bl[row][sseg * 8] = *(const uint4*)(wpl + (size_t)(n0 + row) * CDIM + k0 + sseg * 8);
    }
    __syncthreads();
#pragma unroll
    for (int ks = 0; ks < 2; ++ks) {
      bf16x8 ah[4], al[4], bh_[4], bl_[4];
#pragma unroll
      for (int i = 0; i < 4; ++i) {
        ah[i]  = *(const bf16x8*)&Ah[wm * 64 + i * 16 + r16][ks * 32 + g * 8];
        al[i]  = *(const bf16x8*)&Al[wm * 64 + i * 16 + r16][ks * 32 + g * 8];
        bh_[i] = *(const bf16x8*)&Bh[wn * 64 + i * 16 + r16][ks * 32 + g * 8];
        bl_[i] = *(const bf16x8*)&Bl[wn * 64 + i * 16 + r16][ks * 32 + g * 8];
      }
#pragma unroll
      for (int i = 0; i < 4; ++i)
#pragma unroll
        for (int j = 0; j < 4; ++j) {
          acc[i][j] = __builtin_amdgcn_mfma_f32_16x16x32_bf16(ah[i], bh_[j], acc[i][j], 0, 0, 0);
          acc[i][j] = __builtin_amdgcn_mfma_f32_16x16x32_bf16(ah[i], bl_[j], acc[i][j], 0, 0, 0);
          acc[i][j] = __builtin_amdgcn_mfma_f32_16x16x32_bf16(al[i], bh_[j], acc[i][j], 0, 0, 0);
        }
    }
  }
#pragma unroll
  for (int i = 0; i < 4; ++i) {
    int rb = row0 + wm * 64 + i * 16 + 4 * g;
#pragma unroll
    for (int j = 0; j < 4; ++j) {
      int col = n0 + wn * 64 + j * 16 + r16;
      float bpv = bproj[col];
      f32x4 v = acc[i][j];
#pragma unroll
      for (int r = 0; r < 4; ++r) {
        int rr = rb + r;
        int b = rr / NPIX, p = rr - b * NPIX;
        out[((size_t)b * NTOK + 1 + p) * CDIM + col] = v[r] + bpv;
      }
    }
  }
}

// ---------------- K5: x0 output projection (tiny) ----------------
__global__ void k_x0proj(const float* __restrict__ x0pre, const float* __restrict__ wprojg,
                         const float* __restrict__ bprojg, float* __restrict__ out)
{
  int b = blockIdx.x, c = threadIdx.x;
  __shared__ float xr[CDIM];
  xr[c] = x0pre[(size_t)b * CDIM + c];
  __syncthreads();
  float acc = bprojg[c];
  for (int kk = 0; kk < CDIM; ++kk) acc += xr[kk] * wprojg[(size_t)kk * CDIM + c];
  out[(size_t)b * NTOK * CDIM + c] = acc;
}

extern "C" void kernel_launch(void* const* d_in, const int* in_sizes, int n_in,
                              void* d_out, int out_size, void* d_ws, size_t ws_size,
                              hipStream_t stream)
{
  const float* x      = (const float*)d_in[0];
  const float* wq     = (const float*)d_in[1];
  const float* wkv    = (const float*)d_in[2];
  const float* wproj  = (const float*)d_in[3];
  const float* bproj  = (const float*)d_in[4];
  const float* wqg    = (const float*)d_in[5];
  const float* wkvg   = (const float*)d_in[6];
  const float* wprojg = (const float*)d_in[7];
  const float* bprojg = (const float*)d_in[8];
  const float* lbt    = (const float*)d_in[9];
  const float* g2l    = (const float*)d_in[10];
  const float* g2g    = (const float*)d_in[11];
  const int*   rel    = (const int*)d_in[12];
  float* out = (float*)d_out;

  char* wsb = (char*)d_ws;
  u16* qb = (u16*)wsb;      wsb += (size_t)BATCH * NHEAD * NPIX * MDIM * 2;
  u16* kb = (u16*)wsb;      wsb += (size_t)BATCH * NHEAD * NTOK * MDIM * 2;
  u16* vb = (u16*)wsb;      wsb += (size_t)BATCH * NHEAD * NTOK * MDIM * 2;
  float* kgb = (float*)wsb; wsb += (size_t)BATCH * NHEAD * NTOK * MDIM * 4;
  float* vgb = (float*)wsb; wsb += (size_t)BATCH * NHEAD * NTOK * MDIM * 4;
  u16* x1h = (u16*)wsb;     wsb += (size_t)BATCH * NPIX * CDIM * 2;
  u16* x1l = (u16*)wsb;     wsb += (size_t)BATCH * NPIX * CDIM * 2;
  float* x0pre = (float*)wsb; wsb += (size_t)BATCH * CDIM * 4;
  float* bias_pk = (float*)wsb; wsb += (size_t)NHEAD * 4 * NT * 64 * 4 * 4;
  u16* xb = (u16*)wsb;      wsb += (size_t)NROWP * CDIM * 2;
  u16* Wt = (u16*)wsb;      wsb += (size_t)1920 * CDIM * 2;
  u16* wph = (u16*)wsb;     wsb += (size_t)CDIM * CDIM * 2;
  u16* wpl = (u16*)wsb;     wsb += (size_t)CDIM * CDIM * 2;
  int* ktokA = (int*)wsb;   wsb += (size_t)64 * NKEYP * 4;
  int* ktokL = (int*)wsb;   wsb += (size_t)64 * NKEYP * 4;
  float* mskf = (float*)wsb; wsb += (size_t)64 * NKEYP * 4;

  k_prep_x<<<(NROWP * CDIM / 8 + 255) / 256, 256, 0, stream>>>(x, xb);
  dim3 gw(30, 6);
  k_prep_w<<<gw, 256, 0, stream>>>(wq, wkv, wkvg, Wt);
  dim3 gwp(6, 6);
  k_prep_wp<<<gwp, 256, 0, stream>>>(wproj, wph, wpl);
  k_winprep<<<(64 * NKEYP + 255) / 256, 256, 0, stream>>>(ktokA, ktokL, mskf);
  int nbias = NHEAD * 4 * NT * 64;
  k_bias<<<(nbias + 255) / 256, 256, 0, stream>>>(lbt, g2l, rel, bias_pk);

  dim3 g1(NROWP / 128, 1920 / 128);
  k_qkv_mfma<<<g1, 256, 0, stream>>>(xb, Wt, qb, kb, vb, kgb, vgb);

  dim3 g2(64, BATCH * NHEAD);
  k_local<<<g2, 256, 0, stream>>>(qb, kb, vb, bias_pk, ktokA, ktokL, mskf, x1h, x1l);

  k_glob<<<BATCH * NHEAD, 256, 0, stream>>>(x, wqg, kgb, vgb, g2l, g2g, x0pre);

  dim3 g4(BATCH * NPIX / 128, 3);
  k_proj_mfma<<<g4, 256, 0, stream>>>(x1h, x1l, wph, wpl, bproj, out);

  k_x0proj<<<BATCH, CDIM, 0, stream>>>(x0pre, wprojg, bprojg, out);
}